// Round 10
// baseline (1007.228 us; speedup 1.0000x reference)
//
#include <hip/hip_runtime.h>
#include <hip/hip_bf16.h>
#include <cstdint>
#include <cstddef>

typedef __hip_bfloat16 bf16;
typedef __attribute__((ext_vector_type(8))) short short8;   // 8 bf16 in 4 VGPRs
typedef __attribute__((ext_vector_type(4))) short short4v;
typedef __attribute__((ext_vector_type(4))) float f32x4;
#define DEVI __device__ __forceinline__

constexpr int Bb = 2, Ll = 6273, Pp = 1568, LL2 = 1569, LP = 1600;
constexpr float QK_SCALE = 0.04419417382415922f;  // 512^-0.5

DEVI short f2bs(float f) {
  __hip_bfloat16 h = __float2bfloat16(f);
  return __builtin_bit_cast(short, h);
}
DEVI float bs2f(short s) {
  __hip_bfloat16 h = __builtin_bit_cast(__hip_bfloat16, s);
  return __bfloat162float(h);
}

// async global->LDS, 16B per lane. LDS dest = wave-uniform base + lane*16.
DEVI void gload16(const short* g, short* l) {
  __builtin_amdgcn_global_load_lds(
      (const __attribute__((address_space(1))) void*)g,
      (__attribute__((address_space(3))) void*)l,
      16, 0, 0);
}

// ===========================================================================
// 128x128 MFMA tile cores, BK=64, 256 threads = 4 waves in 2x2.
// PROVEN schedule: single-buffer stage -> sync -> mma -> sync (R1).
// Register ledger (R5-R8, settled):
//  - no __launch_bounds__ => 128-reg cap => wide acc spills (R5/R6).
//  - __launch_bounds__(256) uncapped => 280 regs => 1 blk/CU (R7).
//  - __launch_bounds__(256,2) + b-shared mma128_dual => 96 VGPR + 128 AGPR
//    = 224 <= 256 => 2 waves/SIMD, no spill (R8). R10 extends this proven
//    dual-A pattern to logits/av/weff (B-tile shared by two A-tiles:
//    staging -25%, B-traffic -50%).
// 16B-slot XOR swizzle (slot ^= row&7) -> conflict-free b128 reads.
// Staging: global_load_lds LINEAR dest + inverse-swizzled per-lane global
// SOURCE (rule 21). C/D layout per m89: col=lane&15, row=quad*4+e.
// ===========================================================================
constexpr int BK = 64;

DEVI int sw_idx(int row, int slot) {            // slot = 16B unit (8 shorts)
  return row * BK + (((slot) ^ (row & 7)) << 3);
}

DEVI void mma128(const short* As, const short* Bs, int lane, int wr, int wc,
                 f32x4 (&acc)[4][4]) {
  int m = lane & 15, quad = lane >> 4;
  #pragma unroll
  for (int kh = 0; kh < 2; ++kh) {
    int slot = kh * 4 + quad;
    short8 a[4], b[4];
    #pragma unroll
    for (int i = 0; i < 4; ++i) {
      int row = wr * 64 + i * 16 + m;
      a[i] = *(const short8*)(As + sw_idx(row, slot));
    }
    #pragma unroll
    for (int j = 0; j < 4; ++j) {
      int row = wc * 64 + j * 16 + m;
      b[j] = *(const short8*)(Bs + sw_idx(row, slot));
    }
    #pragma unroll
    for (int i = 0; i < 4; ++i)
      #pragma unroll
      for (int j = 0; j < 4; ++j)
        acc[i][j] = __builtin_amdgcn_mfma_f32_16x16x32_bf16(a[i], b[j], acc[i][j], 0, 0, 0);
  }
}

// Dual-A core: loads shared b[4] ONCE for two A-tiles.
DEVI void mma128_dual(const short* As0, const short* As1, const short* Bs,
                      int lane, int wr, int wc,
                      f32x4 (&acc0)[4][4], f32x4 (&acc1)[4][4]) {
  int m = lane & 15, quad = lane >> 4;
  #pragma unroll
  for (int kh = 0; kh < 2; ++kh) {
    int slot = kh * 4 + quad;
    short8 b[4];
    #pragma unroll
    for (int j = 0; j < 4; ++j)
      b[j] = *(const short8*)(Bs + sw_idx(wc * 64 + j * 16 + m, slot));
    #pragma unroll
    for (int i = 0; i < 4; ++i) {
      int row = wr * 64 + i * 16 + m;
      short8 a0 = *(const short8*)(As0 + sw_idx(row, slot));
      short8 a1 = *(const short8*)(As1 + sw_idx(row, slot));
      #pragma unroll
      for (int j = 0; j < 4; ++j) {
        acc0[i][j] = __builtin_amdgcn_mfma_f32_16x16x32_bf16(a0, b[j], acc0[i][j], 0, 0, 0);
        acc1[i][j] = __builtin_amdgcn_mfma_f32_16x16x32_bf16(a1, b[j], acc1[i][j], 0, 0, 0);
      }
    }
  }
}

// ---------------------------------------------------------------------------
__global__ void emb_kernel(float* __restrict__ embz) {
  int idx = blockIdx.x * 256 + threadIdx.x;
  if (idx >= LP * 512) return;
  int p = idx >> 9, d = idx & 511;
  float v = 0.f;
  if (p > 0 && p < LL2) {
    int pb = p - 1;
    int t = pb / 196, r = pb % 196;
    int h = r / 14, ww = r % 14;
    int pos, j, half;
    if (d < 170)      { pos = t;  j = d;       half = 85; }
    else if (d < 340) { pos = h;  j = d - 170; half = 85; }
    else              { pos = ww; j = d - 340; half = 86; }
    int jj = (j < half) ? j : (j - half);
    float omega = powf(10000.f, -(float)jj / (float)half);
    float ang = (float)pos * omega;
    v = (j < half) ? sinf(ang) : cosf(ang);
  }
  embz[idx] = v;
}

// f32 -> bf16 bulk convert, 4 elements/thread
__global__ void cvt_kernel(const float* __restrict__ src, short* __restrict__ dst, int n4) {
  int idx = blockIdx.x * 256 + threadIdx.x;
  if (idx >= n4) return;
  float4 v = *(const float4*)(src + (size_t)idx * 4);
  short4v o = { f2bs(v.x), f2bs(v.y), f2bs(v.z), f2bs(v.w) };
  *(short4v*)(dst + (size_t)idx * 4) = o;
}

// wpT[n][tap*512+k] = bf16(wp[n*2048 + k*4 + tap])  (works for wpx/wpq/wpk/wpv)
__global__ void wpxt_kernel(const float* __restrict__ wp, short* __restrict__ wpT) {
  int idx = blockIdx.x * 256 + threadIdx.x;
  if (idx >= 512 * 2048) return;
  int n = idx >> 11, rem = idx & 2047, tap = rem >> 9, k = rem & 511;
  wpT[idx] = f2bs(wp[n * 2048 + k * 4 + tap]);
}

// WT[h][k][i] = bf16(W[(h*512+i)*512 + k])
__global__ void tr_w_kernel(const float* __restrict__ W, short* __restrict__ WT) {
  __shared__ float Ws[64][65];
  int i0 = blockIdx.x * 64, k0 = blockIdx.y * 64, h = blockIdx.z;
  int tid = threadIdx.x;
  int r = tid >> 2, c0 = (tid & 3) * 16;
  const float* src = W + ((size_t)(h * 512 + i0 + r)) * 512 + k0 + c0;
  #pragma unroll
  for (int j = 0; j < 16; ++j) Ws[r][c0 + j] = src[j];
  __syncthreads();
  short* dst = WT + ((size_t)(h * 512 + k0 + r)) * 512 + i0 + c0;
  #pragma unroll
  for (int j = 0; j < 16; ++j) dst[j] = f2bs(Ws[c0 + j][r]);
}

// ===========================================================================
// weff128x2: dual-A over n-tile pairs; B (WT k-tile) staged once per pair.
// grid (2, 4, 12*CH).
// ===========================================================================
__global__ void __launch_bounds__(256, 2)
weff128x2(const short* __restrict__ wpqT, const short* __restrict__ wpkT,
          const short* __restrict__ wpvT,
          const short* __restrict__ WqT, const short* __restrict__ WkT,
          const short* __restrict__ WvT,
          int h0, int CH, short* __restrict__ Weff) {
  int n00 = blockIdx.x * 256, n01 = n00 + 128;
  int k0 = blockIdx.y * 128;
  int z = blockIdx.z;
  int mat = z / (4 * CH), rem = z % (4 * CH);
  int ch = rem >> 2, tap = rem & 3;
  const short* wpT = mat == 0 ? wpqT : (mat == 1 ? wpkT : wpvT);
  const short* WT  = mat == 0 ? WqT  : (mat == 1 ? WkT  : WvT);
  int h = h0 + ch;
  int tid = threadIdx.x, lane = tid & 63, w = tid >> 6, wr = w >> 1, wc = w & 1;
  int rbase = tid >> 3;
  int ss = ((tid & 7) ^ (rbase & 7)) << 3;
  __shared__ __align__(16) short As0[128 * BK];
  __shared__ __align__(16) short As1[128 * BK];
  __shared__ __align__(16) short Bs[128 * BK];
  f32x4 acc0[4][4] = {};
  f32x4 acc1[4][4] = {};
  for (int kq = 0; kq < 512; kq += BK) {
    #pragma unroll
    for (int p = 0; p < 4; ++p) {
      int row = rbase + 32 * p;
      gload16(wpT + (size_t)(n00 + row) * 2048 + tap * 512 + kq + ss,
              As0 + (32 * p + 8 * w) * BK);
      gload16(wpT + (size_t)(n01 + row) * 2048 + tap * 512 + kq + ss,
              As1 + (32 * p + 8 * w) * BK);
      gload16(WT + ((size_t)(h * 512 + k0 + row)) * 512 + kq + ss,
              Bs + (32 * p + 8 * w) * BK);
    }
    __syncthreads();
    mma128_dual(As0, As1, Bs, lane, wr, wc, acc0, acc1);
    __syncthreads();
  }
  int m = lane & 15, quad = lane >> 4;
  size_t base = ((size_t)(mat * CH + ch) * 512) * 2048 + tap * 512;
  #pragma unroll
  for (int i = 0; i < 4; ++i)
    #pragma unroll
    for (int j = 0; j < 4; ++j)
      #pragma unroll
      for (int e = 0; e < 4; ++e) {
        int nrow = wr * 64 + i * 16 + quad * 4 + e;
        int k = k0 + wc * 64 + j * 16 + m;
        Weff[base + (size_t)(n00 + nrow) * 2048 + k] = f2bs(acc0[i][j][e]);
        Weff[base + (size_t)(n01 + nrow) * 2048 + k] = f2bs(acc1[i][j][e]);
      }
}

// beff[(mat*CH+ch)][n]: wave-per-n, coalesced (R9). grid (3, CH, 4).
__global__ void beff_fused(const float* __restrict__ bq, const float* __restrict__ bk,
                           const float* __restrict__ bv,
                           const float* __restrict__ wpq, const float* __restrict__ wpk,
                           const float* __restrict__ wpv,
                           int h0, int CH, float* __restrict__ beff) {
  int mat = blockIdx.x, ch = blockIdx.y, n0 = blockIdx.z * 128;
  int wv = threadIdx.x >> 6, lane = threadIdx.x & 63;
  const float* bias = mat == 0 ? bq : (mat == 1 ? bk : bv);
  const float* wp = mat == 0 ? wpq : (mat == 1 ? wpk : wpv);
  float bi[8];
  #pragma unroll
  for (int t = 0; t < 8; ++t) bi[t] = bias[(h0 + ch) * 512 + lane * 8 + t];
  for (int n = n0 + wv; n < n0 + 128; n += 4) {
    const float* row = wp + (size_t)n * 2048 + lane * 32;
    float s = 0.f;
    #pragma unroll
    for (int t = 0; t < 8; ++t) {
      float4 v = *(const float4*)(row + t * 4);
      s += bi[t] * (v.x + v.y + v.z + v.w);
    }
    #pragma unroll
    for (int off = 32; off; off >>= 1) s += __shfl_down(s, off, 64);
    if (lane == 0) beff[(mat * CH + ch) * 512 + n] = s;
  }
}

// ===========================================================================
// pool128x2: one B-tile shared by TWO A-tiles; PX folded as mat==3 (R9).
// __launch_bounds__(256,2): 96 VGPR + 128 AGPR, 2 waves/SIMD (R8).
// grid 13*(12*CH+4), bijective XCD swizzle (m204).
// ===========================================================================
__global__ void __launch_bounds__(256, 2)
pool128x2(const short* __restrict__ xbf, const short* __restrict__ Weff,
          const short* __restrict__ wpxT,
          const float* __restrict__ beff, const float* __restrict__ embz,
          short* __restrict__ PQ, short* __restrict__ PKf,
          short* __restrict__ PVt, short* __restrict__ PX, int CH) {
  int NT = 12 * CH + 4;
  int nwg = 13 * NT;
  int bid = blockIdx.x;
  int q8 = nwg >> 3, r8 = nwg & 7;
  int xcd = bid & 7, lin = bid >> 3;
  int wgid = (xcd < r8 ? xcd * (q8 + 1) : r8 * (q8 + 1) + (xcd - r8) * q8) + lin;
  int nt = wgid % NT, pr = wgid / NT;
  int mb0 = pr * 2, mb1 = pr * 2 + 1;
  int mt0 = mb0 % 13, b0 = mb0 / 13;
  int mt1 = mb1 % 13, b1 = mb1 / 13;
  int mat, ch, n0t;
  const short* Bsrc;
  if (nt < 12 * CH) {
    mat = nt / (4 * CH); ch = (nt >> 2) % CH; n0t = (nt & 3) * 128;
    Bsrc = Weff + (size_t)nt * 128 * 2048;
  } else {
    mat = 3; ch = 0; n0t = (nt - 12 * CH) * 128;
    Bsrc = wpxT + (size_t)n0t * 2048;
  }

  __shared__ __align__(16) short As0[128 * BK];
  __shared__ __align__(16) short As1[128 * BK];
  __shared__ __align__(16) short Bs[128 * BK];
  int tid = threadIdx.x, lane = tid & 63, w = tid >> 6, wr = w >> 1, wc = w & 1;
  int rbase = tid >> 3;
  int ss = ((tid & 7) ^ (rbase & 7)) << 3;
  int srcA0[4], srcA1[4];
  #pragma unroll
  for (int p = 0; p < 4; ++p) {
    int row = rbase + 32 * p;
    int pb0 = mt0 * 128 + row; if (pb0 > Pp - 1) pb0 = Pp - 1;
    int t3 = pb0 / 196, rm = pb0 % 196, h2 = rm / 14, w2 = rm % 14;
    srcA0[p] = b0 * (Ll * 512) + (1 + t3 * 784 + h2 * 56 + w2 * 2) * 512;
    int pb1 = mt1 * 128 + row; if (pb1 > Pp - 1) pb1 = Pp - 1;
    int t3b = pb1 / 196, rmb = pb1 % 196, h2b = rmb / 14, w2b = rmb % 14;
    srcA1[p] = b1 * (Ll * 512) + (1 + t3b * 784 + h2b * 56 + w2b * 2) * 512;
  }

  f32x4 acc0[4][4] = {};
  f32x4 acc1[4][4] = {};
  for (int kq = 0; kq < 2048; kq += BK) {
    int tap = kq >> 9, koff = kq & 511;
    int tr = ((tap & 1) + (tap >> 1) * 28) * 512;
    #pragma unroll
    for (int p = 0; p < 4; ++p) {
      int row = rbase + 32 * p;
      gload16(xbf + (size_t)(srcA0[p] + tr + koff + ss), As0 + (32 * p + 8 * w) * BK);
      gload16(xbf + (size_t)(srcA1[p] + tr + koff + ss), As1 + (32 * p + 8 * w) * BK);
      gload16(Bsrc + (size_t)row * 2048 + kq + ss, Bs + (32 * p + 8 * w) * BK);
    }
    __syncthreads();
    mma128_dual(As0, As1, Bs, lane, wr, wc, acc0, acc1);
    __syncthreads();
  }
  int m = lane & 15, quad = lane >> 4;
  int bb = (mat < 3 ? (mat * CH + ch) : 0) * 512;
  {
    int cg = b0 * CH + ch;
    #pragma unroll
    for (int i = 0; i < 4; ++i)
      #pragma unroll
      for (int j = 0; j < 4; ++j)
        #pragma unroll
        for (int e = 0; e < 4; ++e) {
          int row = wr * 64 + i * 16 + quad * 4 + e;
          int pb = mt0 * 128 + row;
          if (pb >= Pp) continue;
          int tok = pb + 1;
          int n = n0t + wc * 64 + j * 16 + m;
          float bv = (mat < 3) ? beff[bb + n] : 0.f;
          float val = acc0[i][j][e] + bv;
          if (mat == 0)      PQ[((size_t)cg * LP + tok) * 512 + n] = f2bs(val);
          else if (mat == 1) PKf[((size_t)cg * LP + tok) * 512 + n] =
                                 f2bs(val * QK_SCALE + embz[(size_t)tok * 512 + n]);
          else if (mat == 2) PVt[((size_t)cg * 512 + n) * LP + tok] = f2bs(val);
          else               PX[((size_t)b0 * LP + tok) * 512 + n] = f2bs(val);
        }
  }
  {
    int cg = b1 * CH + ch;
    #pragma unroll
    for (int i = 0; i < 4; ++i)
      #pragma unroll
      for (int j = 0; j < 4; ++j)
        #pragma unroll
        for (int e = 0; e < 4; ++e) {
          int row = wr * 64 + i * 16 + quad * 4 + e;
          int pb = mt1 * 128 + row;
          if (pb >= Pp) continue;
          int tok = pb + 1;
          int n = n0t + wc * 64 + j * 16 + m;
          float bv = (mat < 3) ? beff[bb + n] : 0.f;
          float val = acc1[i][j][e] + bv;
          if (mat == 0)      PQ[((size_t)cg * LP + tok) * 512 + n] = f2bs(val);
          else if (mat == 1) PKf[((size_t)cg * LP + tok) * 512 + n] =
                                 f2bs(val * QK_SCALE + embz[(size_t)tok * 512 + n]);
          else if (mat == 2) PVt[((size_t)cg * 512 + n) * LP + tok] = f2bs(val);
          else               PX[((size_t)b1 * LP + tok) * 512 + n] = f2bs(val);
        }
  }
}

// cls row (token 0): one wave per output dot product. grid(128, 3, 2CH)
__global__ void cls_fast(const short* __restrict__ xbf,
                         const float* __restrict__ Wq, const float* __restrict__ bq,
                         const float* __restrict__ Wk, const float* __restrict__ bk,
                         const float* __restrict__ Wv, const float* __restrict__ bv,
                         int h0, int CH,
                         short* __restrict__ PQ, short* __restrict__ PKf,
                         short* __restrict__ PVt) {
  int cg = blockIdx.z, mat = blockIdx.y;
  int wv = threadIdx.x >> 6, lane = threadIdx.x & 63;
  int n = blockIdx.x * 4 + wv;
  int b = cg / CH, h = h0 + cg % CH;
  const float* W = mat == 0 ? Wq : (mat == 1 ? Wk : Wv);
  const float* bias = mat == 0 ? bq : (mat == 1 ? bk : bv);
  const short* xr = xbf + (size_t)b * Ll * 512;
  const float* wr = W + ((size_t)(h * 512 + n)) * 512;
  float s = 0.f;
  #pragma unroll
  for (int j = 0; j < 8; ++j) {
    int k = lane * 8 + j;
    s += bs2f(xr[k]) * wr[k];
  }
  #pragma unroll
  for (int off = 32; off; off >>= 1) s += __shfl_down(s, off, 64);
  if (lane == 0) {
    s += bias[h * 512 + n];
    if (mat == 0)      PQ[((size_t)cg * LP) * 512 + n] = f2bs(s);
    else if (mat == 1) PKf[((size_t)cg * LP) * 512 + n] = f2bs(s * QK_SCALE);
    else               PVt[((size_t)cg * 512 + n) * LP] = f2bs(s);
  }
}

// PX cls row
__global__ void pxcls_kernel(const float* __restrict__ x, short* __restrict__ PX) {
  int b = blockIdx.x, n = threadIdx.x;
  PX[(size_t)b * LP * 512 + n] = f2bs(x[(size_t)b * Ll * 512 + n]);
}

// cfx[cg][kt] = dot(PQ[cg,0,:], embz[kt,:])
__global__ void cfix_kernel(const short* __restrict__ PQ, const float* __restrict__ embz,
                            int a0, float* __restrict__ cfx) {
  int cg = a0 + blockIdx.y;
  int wv = threadIdx.x >> 6, lane = threadIdx.x & 63;
  int kt = blockIdx.x * 4 + wv;
  if (kt >= LP) return;
  int ktc = kt < LL2 ? kt : (LL2 - 1);
  const short* q0 = PQ + (size_t)cg * LP * 512;
  const float* e = embz + (size_t)ktc * 512;
  float s = 0.f;
  #pragma unroll
  for (int j = 0; j < 8; ++j) {
    int d = lane * 8 + j;
    s += bs2f(q0[d]) * e[d];
  }
  #pragma unroll
  for (int off = 32; off; off >>= 1) s += __shfl_down(s, off, 64);
  if (lane == 0) cfx[(size_t)cg * LP + kt] = s;
}

// ===========================================================================
// logits128x2: dual-A over q-tile pairs; B (PKf k-tile) staged once per pair.
// grid (7, 13, na); pair (12,12) double-writes same values (benign).
// ===========================================================================
__global__ void __launch_bounds__(256, 2)
logits128x2(const short* __restrict__ PQ, const short* __restrict__ PKf,
            const float* __restrict__ cfx, int a0, float* __restrict__ Lg) {
  int qt0 = blockIdx.x * 2, qt1 = qt0 + 1; if (qt1 > 12) qt1 = 12;
  int q00 = qt0 * 128, q01 = qt1 * 128;
  int k0 = blockIdx.y * 128, z = blockIdx.z;
  int cg = a0 + z;
  int tid = threadIdx.x, lane = tid & 63, w = tid >> 6, wr = w >> 1, wc = w & 1;
  int rbase = tid >> 3;
  int ss = ((tid & 7) ^ (rbase & 7)) << 3;
  const short* Aq = PQ + (size_t)cg * LP * 512;
  const short* Bk = PKf + (size_t)cg * LP * 512;
  __shared__ __align__(16) short As0[128 * BK];
  __shared__ __align__(16) short As1[128 * BK];
  __shared__ __align__(16) short Bs[128 * BK];
  f32x4 acc0[4][4] = {};
  f32x4 acc1[4][4] = {};
  for (int kq = 0; kq < 512; kq += BK) {
    #pragma unroll
    for (int p = 0; p < 4; ++p) {
      int row = rbase + 32 * p;
      int a0r = q00 + row; if (a0r > LL2 - 1) a0r = LL2 - 1;
      int a1r = q01 + row; if (a1r > LL2 - 1) a1r = LL2 - 1;
      int br = k0 + row;  if (br > LL2 - 1) br = LL2 - 1;
      gload16(Aq + (size_t)a0r * 512 + kq + ss, As0 + (32 * p + 8 * w) * BK);
      gload16(Aq + (size_t)a1r * 512 + kq + ss, As1 + (32 * p + 8 * w) * BK);
      gload16(Bk + (size_t)br * 512 + kq + ss, Bs + (32 * p + 8 * w) * BK);
    }
    __syncthreads();
    mma128_dual(As0, As1, Bs, lane, wr, wc, acc0, acc1);
    __syncthreads();
  }
  int m = lane & 15, quad = lane >> 4;
  float* lg = Lg + (size_t)z * LP * LP;
  const float* cf = cfx + (size_t)cg * LP;
  #pragma unroll
  for (int i = 0; i < 4; ++i)
    #pragma unroll
    for (int j = 0; j < 4; ++j)
      #pragma unroll
      for (int e = 0; e < 4; ++e) {
        int rloc = wr * 64 + i * 16 + quad * 4 + e;
        int kt = k0 + wc * 64 + j * 16 + m;
        if (kt >= LP) continue;
        int qa = q00 + rloc;
        if (qa < LP) {
          float val = acc0[i][j][e];
          if (qa == 0) val -= cf[kt];
          lg[(size_t)qa * LP + kt] = val;
        }
        int qb = q01 + rloc;
        if (qb < LP) {
          float val = acc1[i][j][e];
          if (qb == 0) val -= cf[kt];
          lg[(size_t)qb * LP + kt] = val;
        }
      }
}

// softmax: wave-per-row single-pass (R9). grid (ceil(LL2/4), na).
__global__ void softmax_kernel(float* __restrict__ Lg) {
  int z = blockIdx.y;
  int wv = threadIdx.x >> 6, lane = threadIdx.x & 63;
  int q = blockIdx.x * 4 + wv;
  if (q >= LL2) return;
  float* p = Lg + ((size_t)z * LP + q) * LP;
  float vbuf[28];
  float mx = -1e30f;
  #pragma unroll
  for (int it = 0; it < 7; ++it) {
    int j = it * 256 + lane * 4;
    float4 v;
    if (j < LP) v = *(const float4*)(p + j);
    else        v = make_float4(0.f, 0.f, 0.f, 0.f);
    #pragma unroll
    for (int e = 0; e < 4; ++e) {
      float f = (&v.x)[e];
      float masked = ((j + e) < LL2) ? f : -1e30f;
      vbuf[it * 4 + e] = masked;
      mx = fmaxf(mx, masked);
    }
  }
  #pragma unroll
  for (int off = 32; off; off >>= 1) mx = fmaxf(mx, __shfl_xor(mx, off, 64));
  float sum = 0.f;
  #pragma unroll
  for (int it = 0; it < 7; ++it)
    #pragma unroll
    for (int e = 0; e < 4; ++e) {
      float ev = __expf(vbuf[it * 4 + e] - mx);
      vbuf[it * 4 + e] = ev;
      sum += ev;
    }
  #pragma unroll
  for (int off = 32; off; off >>= 1) sum += __shfl_xor(sum, off, 64);
  float inv = 1.f / sum;
  short* o = (short*)p;
  #pragma unroll
  for (int it = 0; it < 7; ++it) {
    int j = it * 256 + lane * 4;
    if (j < LP) {
      short4v ov = { f2bs(vbuf[it * 4 + 0] * inv), f2bs(vbuf[it * 4 + 1] * inv),
                     f2bs(vbuf[it * 4 + 2] * inv), f2bs(vbuf[it * 4 + 3] * inv) };
      *(short4v*)(o + j) = ov;
    }
  }
}

// ===========================================================================
// av128x2: dual-A over q-tile pairs; B (PVt n-tile) staged once per pair.
// grid (7, 4, na); pair (12,12) double-writes same values (benign).
// ===========================================================================
__global__ void __launch_bounds__(256, 2)
av128x2(const float* __restrict__ Lg, const short* __restrict__ PVt,
        const short* __restrict__ PQ, short* __restrict__ Outb,
        int h0, int CH, int a0) {
  int qt0 = blockIdx.x * 2, qt1 = qt0 + 1; if (qt1 > 12) qt1 = 12;
  int q00 = qt0 * 128, q01 = qt1 * 128;
  int n0 = blockIdx.y * 128, z = blockIdx.z;
  int cg = a0 + z;
  int b = cg / CH, gg = b * 8 + h0 + cg % CH;
  int tid = threadIdx.x, lane = tid & 63, w = tid >> 6, wr = w >> 1, wc = w & 1;
  int rbase = tid >> 3;
  int ss = ((tid & 7) ^ (rbase & 7)) << 3;
  const short* Aat = (const short*)(Lg + (size_t)z * LP * LP);  // bf16, stride 2*LP
  const short* Bv = PVt + (size_t)cg * 512 * LP;
  __shared__ __align__(16) short As0[128 * BK];
  __shared__ __align__(16) short As1[128 * BK];
  __shared__ __align__(16) short Bs[128 * BK];
  f32x4 acc0[4][4] = {};
  f32x4 acc1[4][4] = {};
  for (int kq = 0; kq < LP; kq += BK) {
    #pragma unroll
    for (int p = 0; p < 4; ++p) {
      int row = rbase + 32 * p;
      int a0r = q00 + row; if (a0r > LP - 1) a0r = LP - 1;
      int a1r = q01 + row; if (a1r > LP - 1) a1r = LP - 1;
      gload16(Aat + (size_t)a0r * (2 * LP) + kq + ss, As0 + (32 * p + 8 * w) * BK);
      gload16(Aat + (size_t)a1r * (2 * LP) + kq + ss, As1 + (32 * p + 8 * w) * BK);
      gload16(Bv + (size_t)(n0 + row) * LP + kq + ss, Bs + (32 * p + 8 * w) * BK);
    }
    __syncthreads();
    mma128_dual(As0, As1, Bs, lane, wr, wc, acc0, acc1);
    __syncthreads();
  }
  int m = lane & 15, quad = lane >> 4;
  #pragma unroll
  for (int i = 0; i < 4; ++i)
    #pragma unroll
    for (int j = 0; j < 4; ++j)
      #pragma unroll
      for (int e = 0; e < 4; ++e) {
        int rloc = wr * 64 + i * 16 + quad * 4 + e;
        int n = n0 + wc * 64 + j * 16 + m;
        int qa = q00 + rloc;
        if (qa < LL2) {
          float res = bs2f(PQ[((size_t)cg * LP + qa) * 512 + n]);
          float val = acc0[i][j][e] + (qa == 0 ? 1.f : 2.f) * res;
          Outb[((size_t)gg * LP + qa) * 512 + n] = f2bs(val);
        }
        int qb = q01 + rloc;
        if (qb < LL2) {
          float res = bs2f(PQ[((size_t)cg * LP + qb) * 512 + n]);
          float val = acc1[i][j][e] + (qb == 0 ? 1.f : 2.f) * res;
          Outb[((size_t)gg * LP + qb) * 512 + n] = f2bs(val);
        }
      }
}

// ===========================================================================
// final128: Y = stacked @ Wd^T + bd + PX. grid (25, 4). M=3138 flat (b,q).
// ===========================================================================
__global__ void final128(const short* __restrict__ Outb, const short* __restrict__ WdB,
                         const float* __restrict__ bd, const short* __restrict__ PX,
                         float* __restrict__ Y) {
  __shared__ __align__(16) short As[128 * BK];
  __shared__ __align__(16) short Bs[128 * BK];
  int mf0 = blockIdx.x * 128, n0 = blockIdx.y * 128;
  int tid = threadIdx.x, lane = tid & 63, w = tid >> 6, wr = w >> 1, wc = w & 1;
  int rbase = tid >> 3;
  int ss = ((tid & 7) ^ (rbase & 7)) << 3;
  const int M = Bb * LL2;  // 3138
  int brow[4], qrow[4];
  #pragma unroll
  for (int p = 0; p < 4; ++p) {
    int mf = mf0 + rbase + 32 * p; if (mf > M - 1) mf = M - 1;
    brow[p] = mf / LL2; qrow[p] = mf % LL2;
  }
  f32x4 acc[4][4] = {};
  for (int kq = 0; kq < 4096; kq += BK) {
    int hh = kq >> 9, koff = kq & 511;
    #pragma unroll
    for (int p = 0; p < 4; ++p) {
      int row = rbase + 32 * p;
      gload16(Outb + ((size_t)(brow[p] * 8 + hh) * LP + qrow[p]) * 512 + koff + ss,
              As + (32 * p + 8 * w) * BK);
      gload16(WdB + (size_t)(n0 + row) * 4096 + kq + ss,
              Bs + (32 * p + 8 * w) * BK);
    }
    __syncthreads();
    mma128(As, Bs, lane, wr, wc, acc);
    __syncthreads();
  }
  int m = lane & 15, quad = lane >> 4;
  #pragma unroll
  for (int i = 0; i < 4; ++i)
    #pragma unroll
    for (int j = 0; j < 4; ++j)
      #pragma unroll
      for (int e = 0; e < 4; ++e) {
        int mf = mf0 + wr * 64 + i * 16 + quad * 4 + e;
        if (mf >= M) continue;
        int b2 = mf / LL2, q2 = mf % LL2;
        int dm = n0 + wc * 64 + j * 16 + m;
        float val = acc[i][j][e] + bd[dm] + bs2f(PX[((size_t)b2 * LP + q2) * 512 + dm]);
        Y[(size_t)mf * 512 + dm] = val;
      }
}

// LayerNorm over 512
__global__ void ln_kernel(const float* __restrict__ Y, const float* __restrict__ gamma,
                          const float* __restrict__ beta, float* __restrict__ Outp) {
  int row = blockIdx.x;
  const float* y = Y + (size_t)row * 512;
  __shared__ float red[256];
  int tid = threadIdx.x;
  float v0 = y[tid], v1 = y[tid + 256];
  red[tid] = v0 + v1; __syncthreads();
  for (int s = 128; s; s >>= 1) { if (tid < s) red[tid] += red[tid + s]; __syncthreads(); }
  float mu = red[0] * (1.f / 512.f);
  __syncthreads();
  float d0 = v0 - mu, d1 = v1 - mu;
  red[tid] = d0 * d0 + d1 * d1; __syncthreads();
  for (int s = 128; s; s >>= 1) { if (tid < s) red[tid] += red[tid + s]; __syncthreads(); }
  float rstd = rsqrtf(red[0] * (1.f / 512.f) + 1e-5f);
  float* o = Outp + (size_t)row * 512;
  o[tid]       = d0 * rstd * gamma[tid]       + beta[tid];
  o[tid + 256] = d1 * rstd * gamma[tid + 256] + beta[tid + 256];
}

// ---------------------------------------------------------------------------
extern "C" void kernel_launch(void* const* d_in, const int* in_sizes, int n_in,
                              void* d_out, int out_size, void* d_ws, size_t ws_size,
                              hipStream_t stream) {
  const float* x     = (const float*)d_in[0];
  const float* Wq    = (const float*)d_in[1];
  const float* bq    = (const float*)d_in[2];
  const float* Wk    = (const float*)d_in[3];
  const float* bk    = (const float*)d_in[4];
  const float* Wv    = (const float*)d_in[5];
  const float* bv    = (const float*)d_in[6];
  const float* wpq   = (const float*)d_in[7];
  const float* wpk   = (const float*)d_in[8];
  const float* wpv   = (const float*)d_in[9];
  const float* wpx   = (const float*)d_in[10];
  const float* Wd    = (const float*)d_in[11];
  const float* bd    = (const float*)d_in[12];
  const float* gamma = (const float*)d_in[13];
  const float* beta  = (const float*)d_in[14];
  float* outp = (float*)d_out;

  auto rnd = [](size_t b) { return (b + 255) / 256 * 256; };
  const size_t persist =
      rnd((size_t)LP * 512 * 4) +            // embz
      rnd((size_t)Bb * Ll * 512 * 2) +       // xbf
      4 * rnd((size_t)512 * 2048 * 2) +      // wpxT + wpqT/wpkT/wpvT
      3 * rnd((size_t)8 * 512 * 512 * 2) +   // WqT/WkT/WvT
      rnd((size_t)512 * 4096 * 2) +          // WdB
      rnd((size_t)16 * LP * 512 * 2) +       // Outb
      rnd((size_t)2 * LP * 512 * 2) +        // PX
      rnd((size_t)2 * LL2 * 512 * 4) +       // Y
      rnd((size_t)16 * LP * 4);              // cfx
  auto chpart = [&](int CH) {
    return rnd((size_t)3 * CH * 512 * 2048 * 2) + rnd((size_t)3 * CH * 512 * 4) +
           3 * rnd((size_t)2 * CH * LP * 512 * 2);
  };
  const size_t lgbytes = rnd((size_t)LP * LP * 4);
  int CH = 8;
  while (CH > 1 && persist + chpart(CH) + lgbytes > ws_size) CH >>= 1;
  if (persist + chpart(CH) + lgbytes > ws_size) return;
  int NA = (int)((ws_size - persist - chpart(CH)) / lgbytes);
  if (NA > 2 * CH) NA = 2 * CH;
  int nc = 8 / CH;

  char* w = (char*)d_ws;
  auto alloc = [&](size_t bytes) { char* p = w; w += (bytes + 255) / 256 * 256; return p; };
  float* embz = (float*)alloc((size_t)LP * 512 * 4);
  short* xbf  = (short*)alloc((size_t)Bb * Ll * 512 * 2);
  short* wpxT = (short*)alloc((size_t)512 * 2048 * 2);
  short* wpqT = (short*)alloc((size_t)512 * 2048 * 2);
  short* wpkT = (short*)alloc((size_t)512 * 2048 * 2);
  short* wpvT = (short*)alloc((size_t)512 * 2048 * 2);
  short* WqT  = (short*)alloc((size_t)8 * 512 * 512 * 2);
  short* WkT  = (short*)alloc((size_t)8 * 512 * 512 * 2);
  short* WvT  = (short*)alloc((size_t)8 * 512 * 512 * 2);
  short* WdB  = (short*)alloc((size_t)512 * 4096 * 2);
  short* Outb = (short*)alloc((size_t)16 * LP * 512 * 2);
  short* PX   = (short*)alloc((size_t)2 * LP * 512 * 2);
  float* Y    = (float*)alloc((size_t)2 * LL2 * 512 * 4);
  float* cfx  = (float*)alloc((size_t)16 * LP * 4);
  short* Weff = (short*)alloc((size_t)3 * CH * 512 * 2048 * 2);
  float* beff = (float*)alloc((size_t)3 * CH * 512 * 4);
  short* PQ   = (short*)alloc((size_t)2 * CH * LP * 512 * 2);
  short* PKf  = (short*)alloc((size_t)2 * CH * LP * 512 * 2);
  short* PVt  = (short*)alloc((size_t)2 * CH * LP * 512 * 2);
  float* Lg   = (float*)alloc((size_t)NA * LP * LP * 4);

  dim3 blk(256);
  emb_kernel<<<dim3((LP * 512 + 255) / 256), blk, 0, stream>>>(embz);
  cvt_kernel<<<dim3((Bb * Ll * 512 / 4 + 255) / 256), blk, 0, stream>>>(x, xbf, Bb * Ll * 512 / 4);
  wpxt_kernel<<<dim3(4096), blk, 0, stream>>>(wpx, wpxT);
  wpxt_kernel<<<dim3(4096), blk, 0, stream>>>(wpq, wpqT);
  wpxt_kernel<<<dim3(4096), blk, 0, stream>>>(wpk, wpkT);
  wpxt_kernel<<<dim3(4096), blk, 0, stream>>>(wpv, wpvT);
  tr_w_kernel<<<dim3(8, 8, 8), blk, 0, stream>>>(Wq, WqT);
  tr_w_kernel<<<dim3(8, 8, 8), blk, 0, stream>>>(Wk, WkT);
  tr_w_kernel<<<dim3(8, 8, 8), blk, 0, stream>>>(Wv, WvT);
  cvt_kernel<<<dim3((512 * 4096 / 4 + 255) / 256), blk, 0, stream>>>(Wd, WdB, 512 * 4096 / 4);
  pxcls_kernel<<<dim3(2), dim3(512), 0, stream>>>(x, PX);

  for (int c = 0; c < nc; ++c) {
    int h0 = c * CH;
    weff128x2<<<dim3(2, 4, 12 * CH), blk, 0, stream>>>(wpqT, wpkT, wpvT, WqT, WkT, WvT,
                                                       h0, CH, Weff);
    beff_fused<<<dim3(3, CH, 4), blk, 0, stream>>>(bq, bk, bv, wpq, wpk, wpv, h0, CH, beff);
    pool128x2<<<dim3(13 * (12 * CH + 4)), blk, 0, stream>>>(xbf, Weff, wpxT, beff, embz,
                                                            PQ, PKf, PVt, PX, CH);
    cls_fast<<<dim3(128, 3, 2 * CH), blk, 0, stream>>>(xbf, Wq, bq, Wk, bk, Wv, bv,
                                                       h0, CH, PQ, PKf, PVt);
    for (int a0 = 0; a0 < 2 * CH; a0 += NA) {
      int na = (2 * CH - a0) < NA ? (2 * CH - a0) : NA;
      cfix_kernel<<<dim3(400, na), blk, 0, stream>>>(PQ, embz, a0, cfx);
      logits128x2<<<dim3(7, 13, na), blk, 0, stream>>>(PQ, PKf, cfx, a0, Lg);
      softmax_kernel<<<dim3((LL2 + 3) / 4, na), blk, 0, stream>>>(Lg);
      av128x2<<<dim3(7, 4, na), blk, 0, stream>>>(Lg, PVt, PQ, Outb, h0, CH, a0);
    }
  }

  final128<<<dim3(25, 4), blk, 0, stream>>>(Outb, WdB, bd, PX, Y);
  ln_kernel<<<dim3(Bb * LL2), blk, 0, stream>>>(Y, gamma, beta, outp);
}

// Round 11
// 949.769 us; speedup vs baseline: 1.0605x; 1.0605x over previous
//
#include <hip/hip_runtime.h>
#include <hip/hip_bf16.h>
#include <cstdint>
#include <cstddef>

typedef __hip_bfloat16 bf16;
typedef __attribute__((ext_vector_type(8))) short short8;   // 8 bf16 in 4 VGPRs
typedef __attribute__((ext_vector_type(4))) short short4v;
typedef __attribute__((ext_vector_type(4))) float f32x4;
#define DEVI __device__ __forceinline__

constexpr int Bb = 2, Ll = 6273, Pp = 1568, LL2 = 1569, LP = 1600;
constexpr float QK_SCALE = 0.04419417382415922f;  // 512^-0.5

DEVI short f2bs(float f) {
  __hip_bfloat16 h = __float2bfloat16(f);
  return __builtin_bit_cast(short, h);
}
DEVI float bs2f(short s) {
  __hip_bfloat16 h = __builtin_bit_cast(__hip_bfloat16, s);
  return __bfloat162float(h);
}

// async global->LDS, 16B per lane. LDS dest = wave-uniform base + lane*16.
DEVI void gload16(const short* g, short* l) {
  __builtin_amdgcn_global_load_lds(
      (const __attribute__((address_space(1))) void*)g,
      (__attribute__((address_space(3))) void*)l,
      16, 0, 0);
}

// ===========================================================================
// 128x128 MFMA tile cores, BK=64, 256 threads = 4 waves in 2x2.
// PROVEN schedule: single-buffer stage -> sync -> mma -> sync (R1).
// Register ledger (R5-R8) + occupancy ledger (R10, settled):
//  - no __launch_bounds__ => 128-reg cap => wide acc spills (R5/R6).
//  - __launch_bounds__(256) uncapped => 280 regs => 1 blk/CU (R7).
//  - __launch_bounds__(256,2) + b-shared mma128_dual => 224 regs/wave,
//    2 waves/SIMD, no spill (R8) — pays ONLY where B streams from HBM and
//    K is long (pool: K=2048, Weff 25MB). R10: applying it to L2-resident-B,
//    short-K kernels (logits K=512, av, weff) halves occupancy and LOSES
//    ~90us => those stay single-tile high-occupancy.
// 16B-slot XOR swizzle (slot ^= row&7) -> conflict-free b128 reads.
// Staging: global_load_lds LINEAR dest + inverse-swizzled per-lane global
// SOURCE (rule 21). C/D layout per m89: col=lane&15, row=quad*4+e.
// ===========================================================================
constexpr int BK = 64;

DEVI int sw_idx(int row, int slot) {            // slot = 16B unit (8 shorts)
  return row * BK + (((slot) ^ (row & 7)) << 3);
}

DEVI void mma128(const short* As, const short* Bs, int lane, int wr, int wc,
                 f32x4 (&acc)[4][4]) {
  int m = lane & 15, quad = lane >> 4;
  #pragma unroll
  for (int kh = 0; kh < 2; ++kh) {
    int slot = kh * 4 + quad;
    short8 a[4], b[4];
    #pragma unroll
    for (int i = 0; i < 4; ++i) {
      int row = wr * 64 + i * 16 + m;
      a[i] = *(const short8*)(As + sw_idx(row, slot));
    }
    #pragma unroll
    for (int j = 0; j < 4; ++j) {
      int row = wc * 64 + j * 16 + m;
      b[j] = *(const short8*)(Bs + sw_idx(row, slot));
    }
    #pragma unroll
    for (int i = 0; i < 4; ++i)
      #pragma unroll
      for (int j = 0; j < 4; ++j)
        acc[i][j] = __builtin_amdgcn_mfma_f32_16x16x32_bf16(a[i], b[j], acc[i][j], 0, 0, 0);
  }
}

// Dual-A core: loads shared b[4] ONCE for two A-tiles (pool only).
DEVI void mma128_dual(const short* As0, const short* As1, const short* Bs,
                      int lane, int wr, int wc,
                      f32x4 (&acc0)[4][4], f32x4 (&acc1)[4][4]) {
  int m = lane & 15, quad = lane >> 4;
  #pragma unroll
  for (int kh = 0; kh < 2; ++kh) {
    int slot = kh * 4 + quad;
    short8 b[4];
    #pragma unroll
    for (int j = 0; j < 4; ++j)
      b[j] = *(const short8*)(Bs + sw_idx(wc * 64 + j * 16 + m, slot));
    #pragma unroll
    for (int i = 0; i < 4; ++i) {
      int row = wr * 64 + i * 16 + m;
      short8 a0 = *(const short8*)(As0 + sw_idx(row, slot));
      short8 a1 = *(const short8*)(As1 + sw_idx(row, slot));
      #pragma unroll
      for (int j = 0; j < 4; ++j) {
        acc0[i][j] = __builtin_amdgcn_mfma_f32_16x16x32_bf16(a0, b[j], acc0[i][j], 0, 0, 0);
        acc1[i][j] = __builtin_amdgcn_mfma_f32_16x16x32_bf16(a1, b[j], acc1[i][j], 0, 0, 0);
      }
    }
  }
}

// ---------------------------------------------------------------------------
__global__ void emb_kernel(float* __restrict__ embz) {
  int idx = blockIdx.x * 256 + threadIdx.x;
  if (idx >= LP * 512) return;
  int p = idx >> 9, d = idx & 511;
  float v = 0.f;
  if (p > 0 && p < LL2) {
    int pb = p - 1;
    int t = pb / 196, r = pb % 196;
    int h = r / 14, ww = r % 14;
    int pos, j, half;
    if (d < 170)      { pos = t;  j = d;       half = 85; }
    else if (d < 340) { pos = h;  j = d - 170; half = 85; }
    else              { pos = ww; j = d - 340; half = 86; }
    int jj = (j < half) ? j : (j - half);
    float omega = powf(10000.f, -(float)jj / (float)half);
    float ang = (float)pos * omega;
    v = (j < half) ? sinf(ang) : cosf(ang);
  }
  embz[idx] = v;
}

// f32 -> bf16 bulk convert, 4 elements/thread
__global__ void cvt_kernel(const float* __restrict__ src, short* __restrict__ dst, int n4) {
  int idx = blockIdx.x * 256 + threadIdx.x;
  if (idx >= n4) return;
  float4 v = *(const float4*)(src + (size_t)idx * 4);
  short4v o = { f2bs(v.x), f2bs(v.y), f2bs(v.z), f2bs(v.w) };
  *(short4v*)(dst + (size_t)idx * 4) = o;
}

// wpT[n][tap*512+k] = bf16(wp[n*2048 + k*4 + tap])  (works for wpx/wpq/wpk/wpv)
__global__ void wpxt_kernel(const float* __restrict__ wp, short* __restrict__ wpT) {
  int idx = blockIdx.x * 256 + threadIdx.x;
  if (idx >= 512 * 2048) return;
  int n = idx >> 11, rem = idx & 2047, tap = rem >> 9, k = rem & 511;
  wpT[idx] = f2bs(wp[n * 2048 + k * 4 + tap]);
}

// WT[h][k][i] = bf16(W[(h*512+i)*512 + k])
__global__ void tr_w_kernel(const float* __restrict__ W, short* __restrict__ WT) {
  __shared__ float Ws[64][65];
  int i0 = blockIdx.x * 64, k0 = blockIdx.y * 64, h = blockIdx.z;
  int tid = threadIdx.x;
  int r = tid >> 2, c0 = (tid & 3) * 16;
  const float* src = W + ((size_t)(h * 512 + i0 + r)) * 512 + k0 + c0;
  #pragma unroll
  for (int j = 0; j < 16; ++j) Ws[r][c0 + j] = src[j];
  __syncthreads();
  short* dst = WT + ((size_t)(h * 512 + k0 + r)) * 512 + i0 + c0;
  #pragma unroll
  for (int j = 0; j < 16; ++j) dst[j] = f2bs(Ws[c0 + j][r]);
}

// ===========================================================================
// weff128: Weff[(mat*CH+ch)*512+n][tap*512+k] = sum_i wpT[n][tap*512+i]*WT[h][k][i]
// grid (4, 4, 12*CH) — R1 single-buffer schedule, high occupancy (R10 lesson)
// ===========================================================================
__global__ void weff128(const short* __restrict__ wpqT, const short* __restrict__ wpkT,
                        const short* __restrict__ wpvT,
                        const short* __restrict__ WqT, const short* __restrict__ WkT,
                        const short* __restrict__ WvT,
                        int h0, int CH, short* __restrict__ Weff) {
  __shared__ __align__(16) short As[128 * BK];
  __shared__ __align__(16) short Bs[128 * BK];
  int n0 = blockIdx.x * 128, k0 = blockIdx.y * 128;
  int z = blockIdx.z;
  int mat = z / (4 * CH), rem = z % (4 * CH);
  int ch = rem >> 2, tap = rem & 3;
  const short* wpT = mat == 0 ? wpqT : (mat == 1 ? wpkT : wpvT);
  const short* WT  = mat == 0 ? WqT  : (mat == 1 ? WkT  : WvT);
  int h = h0 + ch;
  int tid = threadIdx.x, lane = tid & 63, w = tid >> 6, wr = w >> 1, wc = w & 1;
  int rbase = tid >> 3;
  int ss = ((tid & 7) ^ (rbase & 7)) << 3;   // pre-swizzled source slot (shorts)
  f32x4 acc[4][4] = {};
  for (int kq = 0; kq < 512; kq += BK) {
    #pragma unroll
    for (int p = 0; p < 4; ++p) {
      int row = rbase + 32 * p;
      gload16(wpT + (size_t)(n0 + row) * 2048 + tap * 512 + kq + ss,
              As + (32 * p + 8 * w) * BK);
      gload16(WT + ((size_t)(h * 512 + k0 + row)) * 512 + kq + ss,
              Bs + (32 * p + 8 * w) * BK);
    }
    __syncthreads();
    mma128(As, Bs, lane, wr, wc, acc);
    __syncthreads();
  }
  int m = lane & 15, quad = lane >> 4;
  size_t base = ((size_t)(mat * CH + ch) * 512) * 2048 + tap * 512;
  #pragma unroll
  for (int i = 0; i < 4; ++i)
    #pragma unroll
    for (int j = 0; j < 4; ++j)
      #pragma unroll
      for (int e = 0; e < 4; ++e) {
        int n = n0 + wr * 64 + i * 16 + quad * 4 + e;
        int k = k0 + wc * 64 + j * 16 + m;
        Weff[base + (size_t)n * 2048 + k] = f2bs(acc[i][j][e]);
      }
}

// beff[(mat*CH+ch)][n]: wave-per-n, coalesced (R9). grid (3, CH, 4).
__global__ void beff_fused(const float* __restrict__ bq, const float* __restrict__ bk,
                           const float* __restrict__ bv,
                           const float* __restrict__ wpq, const float* __restrict__ wpk,
                           const float* __restrict__ wpv,
                           int h0, int CH, float* __restrict__ beff) {
  int mat = blockIdx.x, ch = blockIdx.y, n0 = blockIdx.z * 128;
  int wv = threadIdx.x >> 6, lane = threadIdx.x & 63;
  const float* bias = mat == 0 ? bq : (mat == 1 ? bk : bv);
  const float* wp = mat == 0 ? wpq : (mat == 1 ? wpk : wpv);
  float bi[8];
  #pragma unroll
  for (int t = 0; t < 8; ++t) bi[t] = bias[(h0 + ch) * 512 + lane * 8 + t];
  for (int n = n0 + wv; n < n0 + 128; n += 4) {
    const float* row = wp + (size_t)n * 2048 + lane * 32;
    float s = 0.f;
    #pragma unroll
    for (int t = 0; t < 8; ++t) {
      float4 v = *(const float4*)(row + t * 4);
      s += bi[t] * (v.x + v.y + v.z + v.w);
    }
    #pragma unroll
    for (int off = 32; off; off >>= 1) s += __shfl_down(s, off, 64);
    if (lane == 0) beff[(mat * CH + ch) * 512 + n] = s;
  }
}

// ===========================================================================
// pool128x2: one B-tile shared by TWO A-tiles; PX folded as mat==3 (R9).
// __launch_bounds__(256,2): 96 VGPR + 128 AGPR, 2 waves/SIMD, no spill (R8).
// Dual-A pays HERE because B (Weff, 25MB/chunk) streams from HBM and K=2048.
// grid 13*(12*CH+4), bijective XCD swizzle (m204).
// ===========================================================================
__global__ void __launch_bounds__(256, 2)
pool128x2(const short* __restrict__ xbf, const short* __restrict__ Weff,
          const short* __restrict__ wpxT,
          const float* __restrict__ beff, const float* __restrict__ embz,
          short* __restrict__ PQ, short* __restrict__ PKf,
          short* __restrict__ PVt, short* __restrict__ PX, int CH) {
  int NT = 12 * CH + 4;
  int nwg = 13 * NT;
  int bid = blockIdx.x;
  int q8 = nwg >> 3, r8 = nwg & 7;
  int xcd = bid & 7, lin = bid >> 3;
  int wgid = (xcd < r8 ? xcd * (q8 + 1) : r8 * (q8 + 1) + (xcd - r8) * q8) + lin;
  int nt = wgid % NT, pr = wgid / NT;
  int mb0 = pr * 2, mb1 = pr * 2 + 1;
  int mt0 = mb0 % 13, b0 = mb0 / 13;
  int mt1 = mb1 % 13, b1 = mb1 / 13;
  int mat, ch, n0t;
  const short* Bsrc;
  if (nt < 12 * CH) {
    mat = nt / (4 * CH); ch = (nt >> 2) % CH; n0t = (nt & 3) * 128;
    Bsrc = Weff + (size_t)nt * 128 * 2048;
  } else {
    mat = 3; ch = 0; n0t = (nt - 12 * CH) * 128;
    Bsrc = wpxT + (size_t)n0t * 2048;
  }

  __shared__ __align__(16) short As0[128 * BK];
  __shared__ __align__(16) short As1[128 * BK];
  __shared__ __align__(16) short Bs[128 * BK];
  int tid = threadIdx.x, lane = tid & 63, w = tid >> 6, wr = w >> 1, wc = w & 1;
  int rbase = tid >> 3;
  int ss = ((tid & 7) ^ (rbase & 7)) << 3;
  int srcA0[4], srcA1[4];
  #pragma unroll
  for (int p = 0; p < 4; ++p) {
    int row = rbase + 32 * p;
    int pb0 = mt0 * 128 + row; if (pb0 > Pp - 1) pb0 = Pp - 1;
    int t3 = pb0 / 196, rm = pb0 % 196, h2 = rm / 14, w2 = rm % 14;
    srcA0[p] = b0 * (Ll * 512) + (1 + t3 * 784 + h2 * 56 + w2 * 2) * 512;
    int pb1 = mt1 * 128 + row; if (pb1 > Pp - 1) pb1 = Pp - 1;
    int t3b = pb1 / 196, rmb = pb1 % 196, h2b = rmb / 14, w2b = rmb % 14;
    srcA1[p] = b1 * (Ll * 512) + (1 + t3b * 784 + h2b * 56 + w2b * 2) * 512;
  }

  f32x4 acc0[4][4] = {};
  f32x4 acc1[4][4] = {};
  for (int kq = 0; kq < 2048; kq += BK) {
    int tap = kq >> 9, koff = kq & 511;
    int tr = ((tap & 1) + (tap >> 1) * 28) * 512;
    #pragma unroll
    for (int p = 0; p < 4; ++p) {
      int row = rbase + 32 * p;
      gload16(xbf + (size_t)(srcA0[p] + tr + koff + ss), As0 + (32 * p + 8 * w) * BK);
      gload16(xbf + (size_t)(srcA1[p] + tr + koff + ss), As1 + (32 * p + 8 * w) * BK);
      gload16(Bsrc + (size_t)row * 2048 + kq + ss, Bs + (32 * p + 8 * w) * BK);
    }
    __syncthreads();
    mma128_dual(As0, As1, Bs, lane, wr, wc, acc0, acc1);
    __syncthreads();
  }
  int m = lane & 15, quad = lane >> 4;
  int bb = (mat < 3 ? (mat * CH + ch) : 0) * 512;
  {
    int cg = b0 * CH + ch;
    #pragma unroll
    for (int i = 0; i < 4; ++i)
      #pragma unroll
      for (int j = 0; j < 4; ++j)
        #pragma unroll
        for (int e = 0; e < 4; ++e) {
          int row = wr * 64 + i * 16 + quad * 4 + e;
          int pb = mt0 * 128 + row;
          if (pb >= Pp) continue;
          int tok = pb + 1;
          int n = n0t + wc * 64 + j * 16 + m;
          float bv = (mat < 3) ? beff[bb + n] : 0.f;
          float val = acc0[i][j][e] + bv;
          if (mat == 0)      PQ[((size_t)cg * LP + tok) * 512 + n] = f2bs(val);
          else if (mat == 1) PKf[((size_t)cg * LP + tok) * 512 + n] =
                                 f2bs(val * QK_SCALE + embz[(size_t)tok * 512 + n]);
          else if (mat == 2) PVt[((size_t)cg * 512 + n) * LP + tok] = f2bs(val);
          else               PX[((size_t)b0 * LP + tok) * 512 + n] = f2bs(val);
        }
  }
  {
    int cg = b1 * CH + ch;
    #pragma unroll
    for (int i = 0; i < 4; ++i)
      #pragma unroll
      for (int j = 0; j < 4; ++j)
        #pragma unroll
        for (int e = 0; e < 4; ++e) {
          int row = wr * 64 + i * 16 + quad * 4 + e;
          int pb = mt1 * 128 + row;
          if (pb >= Pp) continue;
          int tok = pb + 1;
          int n = n0t + wc * 64 + j * 16 + m;
          float bv = (mat < 3) ? beff[bb + n] : 0.f;
          float val = acc1[i][j][e] + bv;
          if (mat == 0)      PQ[((size_t)cg * LP + tok) * 512 + n] = f2bs(val);
          else if (mat == 1) PKf[((size_t)cg * LP + tok) * 512 + n] =
                                 f2bs(val * QK_SCALE + embz[(size_t)tok * 512 + n]);
          else if (mat == 2) PVt[((size_t)cg * 512 + n) * LP + tok] = f2bs(val);
          else               PX[((size_t)b1 * LP + tok) * 512 + n] = f2bs(val);
        }
  }
}

// cls row (token 0): one wave per output dot product. grid(128, 3, 2CH)
__global__ void cls_fast(const short* __restrict__ xbf,
                         const float* __restrict__ Wq, const float* __restrict__ bq,
                         const float* __restrict__ Wk, const float* __restrict__ bk,
                         const float* __restrict__ Wv, const float* __restrict__ bv,
                         int h0, int CH,
                         short* __restrict__ PQ, short* __restrict__ PKf,
                         short* __restrict__ PVt) {
  int cg = blockIdx.z, mat = blockIdx.y;
  int wv = threadIdx.x >> 6, lane = threadIdx.x & 63;
  int n = blockIdx.x * 4 + wv;
  int b = cg / CH, h = h0 + cg % CH;
  const float* W = mat == 0 ? Wq : (mat == 1 ? Wk : Wv);
  const float* bias = mat == 0 ? bq : (mat == 1 ? bk : bv);
  const short* xr = xbf + (size_t)b * Ll * 512;
  const float* wr = W + ((size_t)(h * 512 + n)) * 512;
  float s = 0.f;
  #pragma unroll
  for (int j = 0; j < 8; ++j) {
    int k = lane * 8 + j;
    s += bs2f(xr[k]) * wr[k];
  }
  #pragma unroll
  for (int off = 32; off; off >>= 1) s += __shfl_down(s, off, 64);
  if (lane == 0) {
    s += bias[h * 512 + n];
    if (mat == 0)      PQ[((size_t)cg * LP) * 512 + n] = f2bs(s);
    else if (mat == 1) PKf[((size_t)cg * LP) * 512 + n] = f2bs(s * QK_SCALE);
    else               PVt[((size_t)cg * 512 + n) * LP] = f2bs(s);
  }
}

// PX cls row
__global__ void pxcls_kernel(const float* __restrict__ x, short* __restrict__ PX) {
  int b = blockIdx.x, n = threadIdx.x;
  PX[(size_t)b * LP * 512 + n] = f2bs(x[(size_t)b * Ll * 512 + n]);
}

// cfx[cg][kt] = dot(PQ[cg,0,:], embz[kt,:])
__global__ void cfix_kernel(const short* __restrict__ PQ, const float* __restrict__ embz,
                            int a0, float* __restrict__ cfx) {
  int cg = a0 + blockIdx.y;
  int wv = threadIdx.x >> 6, lane = threadIdx.x & 63;
  int kt = blockIdx.x * 4 + wv;
  if (kt >= LP) return;
  int ktc = kt < LL2 ? kt : (LL2 - 1);
  const short* q0 = PQ + (size_t)cg * LP * 512;
  const float* e = embz + (size_t)ktc * 512;
  float s = 0.f;
  #pragma unroll
  for (int j = 0; j < 8; ++j) {
    int d = lane * 8 + j;
    s += bs2f(q0[d]) * e[d];
  }
  #pragma unroll
  for (int off = 32; off; off >>= 1) s += __shfl_down(s, off, 64);
  if (lane == 0) cfx[(size_t)cg * LP + kt] = s;
}

// ===========================================================================
// logits128: Lg[z][q][kt] = PQ[cg] . PKf[cg]; row0 -= cfx. grid (13,13,na)
// Single-tile, high occupancy (R10: dual-A here loses).
// ===========================================================================
__global__ void logits128(const short* __restrict__ PQ, const short* __restrict__ PKf,
                          const float* __restrict__ cfx, int a0, float* __restrict__ Lg) {
  __shared__ __align__(16) short As[128 * BK];
  __shared__ __align__(16) short Bs[128 * BK];
  int q0 = blockIdx.x * 128, k0 = blockIdx.y * 128, z = blockIdx.z;
  int cg = a0 + z;
  int tid = threadIdx.x, lane = tid & 63, w = tid >> 6, wr = w >> 1, wc = w & 1;
  int rbase = tid >> 3;
  int ss = ((tid & 7) ^ (rbase & 7)) << 3;
  const short* Aq = PQ + (size_t)cg * LP * 512;
  const short* Bk = PKf + (size_t)cg * LP * 512;
  f32x4 acc[4][4] = {};
  for (int kq = 0; kq < 512; kq += BK) {
    #pragma unroll
    for (int p = 0; p < 4; ++p) {
      int row = rbase + 32 * p;
      int ar = q0 + row; if (ar > LL2 - 1) ar = LL2 - 1;
      int br = k0 + row; if (br > LL2 - 1) br = LL2 - 1;
      gload16(Aq + (size_t)ar * 512 + kq + ss, As + (32 * p + 8 * w) * BK);
      gload16(Bk + (size_t)br * 512 + kq + ss, Bs + (32 * p + 8 * w) * BK);
    }
    __syncthreads();
    mma128(As, Bs, lane, wr, wc, acc);
    __syncthreads();
  }
  int m = lane & 15, quad = lane >> 4;
  float* lg = Lg + (size_t)z * LP * LP;
  const float* cf = cfx + (size_t)cg * LP;
  #pragma unroll
  for (int i = 0; i < 4; ++i)
    #pragma unroll
    for (int j = 0; j < 4; ++j)
      #pragma unroll
      for (int e = 0; e < 4; ++e) {
        int q = q0 + wr * 64 + i * 16 + quad * 4 + e;
        int kt = k0 + wc * 64 + j * 16 + m;
        if (q >= LP || kt >= LP) continue;
        float val = acc[i][j][e];
        if (q == 0) val -= cf[kt];
        lg[(size_t)q * LP + kt] = val;
      }
}

// softmax: wave-per-row single-pass (R9). grid (ceil(LL2/4), na).
__global__ void softmax_kernel(float* __restrict__ Lg) {
  int z = blockIdx.y;
  int wv = threadIdx.x >> 6, lane = threadIdx.x & 63;
  int q = blockIdx.x * 4 + wv;
  if (q >= LL2) return;
  float* p = Lg + ((size_t)z * LP + q) * LP;
  float vbuf[28];
  float mx = -1e30f;
  #pragma unroll
  for (int it = 0; it < 7; ++it) {
    int j = it * 256 + lane * 4;
    float4 v;
    if (j < LP) v = *(const float4*)(p + j);
    else        v = make_float4(0.f, 0.f, 0.f, 0.f);
    #pragma unroll
    for (int e = 0; e < 4; ++e) {
      float f = (&v.x)[e];
      float masked = ((j + e) < LL2) ? f : -1e30f;
      vbuf[it * 4 + e] = masked;
      mx = fmaxf(mx, masked);
    }
  }
  #pragma unroll
  for (int off = 32; off; off >>= 1) mx = fmaxf(mx, __shfl_xor(mx, off, 64));
  float sum = 0.f;
  #pragma unroll
  for (int it = 0; it < 7; ++it)
    #pragma unroll
    for (int e = 0; e < 4; ++e) {
      float ev = __expf(vbuf[it * 4 + e] - mx);
      vbuf[it * 4 + e] = ev;
      sum += ev;
    }
  #pragma unroll
  for (int off = 32; off; off >>= 1) sum += __shfl_xor(sum, off, 64);
  float inv = 1.f / sum;
  short* o = (short*)p;
  #pragma unroll
  for (int it = 0; it < 7; ++it) {
    int j = it * 256 + lane * 4;
    if (j < LP) {
      short4v ov = { f2bs(vbuf[it * 4 + 0] * inv), f2bs(vbuf[it * 4 + 1] * inv),
                     f2bs(vbuf[it * 4 + 2] * inv), f2bs(vbuf[it * 4 + 3] * inv) };
      *(short4v*)(o + j) = ov;
    }
  }
}

// ===========================================================================
// av128: Outb[gg][q][n] = attn @ PVt + (q==0?1:2)*PQ. grid (13,4,na)
// Single-tile, high occupancy (R10: dual-A here loses).
// ===========================================================================
__global__ void av128(const float* __restrict__ Lg, const short* __restrict__ PVt,
                      const short* __restrict__ PQ, short* __restrict__ Outb,
                      int h0, int CH, int a0) {
  __shared__ __align__(16) short As[128 * BK];
  __shared__ __align__(16) short Bs[128 * BK];
  int q0 = blockIdx.x * 128, n0 = blockIdx.y * 128, z = blockIdx.z;
  int cg = a0 + z;
  int b = cg / CH, gg = b * 8 + h0 + cg % CH;
  int tid = threadIdx.x, lane = tid & 63, w = tid >> 6, wr = w >> 1, wc = w & 1;
  int rbase = tid >> 3;
  int ss = ((tid & 7) ^ (rbase & 7)) << 3;
  const short* Aat = (const short*)(Lg + (size_t)z * LP * LP);  // bf16 rows, stride 2*LP
  const short* Bv = PVt + (size_t)cg * 512 * LP;
  f32x4 acc[4][4] = {};
  for (int kq = 0; kq < LP; kq += BK) {
    #pragma unroll
    for (int p = 0; p < 4; ++p) {
      int row = rbase + 32 * p;
      int ar = q0 + row; if (ar > LP - 1) ar = LP - 1;
      gload16(Aat + (size_t)ar * (2 * LP) + kq + ss, As + (32 * p + 8 * w) * BK);
      gload16(Bv + (size_t)(n0 + row) * LP + kq + ss, Bs + (32 * p + 8 * w) * BK);
    }
    __syncthreads();
    mma128(As, Bs, lane, wr, wc, acc);
    __syncthreads();
  }
  int m = lane & 15, quad = lane >> 4;
  #pragma unroll
  for (int i = 0; i < 4; ++i)
    #pragma unroll
    for (int j = 0; j < 4; ++j)
      #pragma unroll
      for (int e = 0; e < 4; ++e) {
        int q = q0 + wr * 64 + i * 16 + quad * 4 + e;
        if (q >= LL2) continue;
        int n = n0 + wc * 64 + j * 16 + m;
        float res = bs2f(PQ[((size_t)cg * LP + q) * 512 + n]);
        float val = acc[i][j][e] + (q == 0 ? 1.f : 2.f) * res;
        Outb[((size_t)gg * LP + q) * 512 + n] = f2bs(val);
      }
}

// ===========================================================================
// final128: Y = stacked @ Wd^T + bd + PX. grid (25, 4). M=3138 flat (b,q).
// ===========================================================================
__global__ void final128(const short* __restrict__ Outb, const short* __restrict__ WdB,
                         const float* __restrict__ bd, const short* __restrict__ PX,
                         float* __restrict__ Y) {
  __shared__ __align__(16) short As[128 * BK];
  __shared__ __align__(16) short Bs[128 * BK];
  int mf0 = blockIdx.x * 128, n0 = blockIdx.y * 128;
  int tid = threadIdx.x, lane = tid & 63, w = tid >> 6, wr = w >> 1, wc = w & 1;
  int rbase = tid >> 3;
  int ss = ((tid & 7) ^ (rbase & 7)) << 3;
  const int M = Bb * LL2;  // 3138
  int brow[4], qrow[4];
  #pragma unroll
  for (int p = 0; p < 4; ++p) {
    int mf = mf0 + rbase + 32 * p; if (mf > M - 1) mf = M - 1;
    brow[p] = mf / LL2; qrow[p] = mf % LL2;
  }
  f32x4 acc[4][4] = {};
  for (int kq = 0; kq < 4096; kq += BK) {
    int hh = kq >> 9, koff = kq & 511;
    #pragma unroll
    for (int p = 0; p < 4; ++p) {
      int row = rbase + 32 * p;
      gload16(Outb + ((size_t)(brow[p] * 8 + hh) * LP + qrow[p]) * 512 + koff + ss,
              As + (32 * p + 8 * w) * BK);
      gload16(WdB + (size_t)(n0 + row) * 4096 + kq + ss,
              Bs + (32 * p + 8 * w) * BK);
    }
    __syncthreads();
    mma128(As, Bs, lane, wr, wc, acc);
    __syncthreads();
  }
  int m = lane & 15, quad = lane >> 4;
  #pragma unroll
  for (int i = 0; i < 4; ++i)
    #pragma unroll
    for (int j = 0; j < 4; ++j)
      #pragma unroll
      for (int e = 0; e < 4; ++e) {
        int mf = mf0 + wr * 64 + i * 16 + quad * 4 + e;
        if (mf >= M) continue;
        int b2 = mf / LL2, q2 = mf % LL2;
        int dm = n0 + wc * 64 + j * 16 + m;
        float val = acc[i][j][e] + bd[dm] + bs2f(PX[((size_t)b2 * LP + q2) * 512 + dm]);
        Y[(size_t)mf * 512 + dm] = val;
      }
}

// LayerNorm over 512
__global__ void ln_kernel(const float* __restrict__ Y, const float* __restrict__ gamma,
                          const float* __restrict__ beta, float* __restrict__ Outp) {
  int row = blockIdx.x;
  const float* y = Y + (size_t)row * 512;
  __shared__ float red[256];
  int tid = threadIdx.x;
  float v0 = y[tid], v1 = y[tid + 256];
  red[tid] = v0 + v1; __syncthreads();
  for (int s = 128; s; s >>= 1) { if (tid < s) red[tid] += red[tid + s]; __syncthreads(); }
  float mu = red[0] * (1.f / 512.f);
  __syncthreads();
  float d0 = v0 - mu, d1 = v1 - mu;
  red[tid] = d0 * d0 + d1 * d1; __syncthreads();
  for (int s = 128; s; s >>= 1) { if (tid < s) red[tid] += red[tid + s]; __syncthreads(); }
  float rstd = rsqrtf(red[0] * (1.f / 512.f) + 1e-5f);
  float* o = Outp + (size_t)row * 512;
  o[tid]       = d0 * rstd * gamma[tid]       + beta[tid];
  o[tid + 256] = d1 * rstd * gamma[tid + 256] + beta[tid + 256];
}

// ---------------------------------------------------------------------------
extern "C" void kernel_launch(void* const* d_in, const int* in_sizes, int n_in,
                              void* d_out, int out_size, void* d_ws, size_t ws_size,
                              hipStream_t stream) {
  const float* x     = (const float*)d_in[0];
  const float* Wq    = (const float*)d_in[1];
  const float* bq    = (const float*)d_in[2];
  const float* Wk    = (const float*)d_in[3];
  const float* bk    = (const float*)d_in[4];
  const float* Wv    = (const float*)d_in[5];
  const float* bv    = (const float*)d_in[6];
  const float* wpq   = (const float*)d_in[7];
  const float* wpk   = (const float*)d_in[8];
  const float* wpv   = (const float*)d_in[9];
  const float* wpx   = (const float*)d_in[10];
  const float* Wd    = (const float*)d_in[11];
  const float* bd    = (const float*)d_in[12];
  const float* gamma = (const float*)d_in[13];
  const float* beta  = (const float*)d_in[14];
  float* outp = (float*)d_out;

  auto rnd = [](size_t b) { return (b + 255) / 256 * 256; };
  const size_t persist =
      rnd((size_t)LP * 512 * 4) +            // embz
      rnd((size_t)Bb * Ll * 512 * 2) +       // xbf
      4 * rnd((size_t)512 * 2048 * 2) +      // wpxT + wpqT/wpkT/wpvT
      3 * rnd((size_t)8 * 512 * 512 * 2) +   // WqT/WkT/WvT
      rnd((size_t)512 * 4096 * 2) +          // WdB
      rnd((size_t)16 * LP * 512 * 2) +       // Outb
      rnd((size_t)2 * LP * 512 * 2) +        // PX
      rnd((size_t)2 * LL2 * 512 * 4) +       // Y
      rnd((size_t)16 * LP * 4);              // cfx
  auto chpart = [&](int CH) {
    return rnd((size_t)3 * CH * 512 * 2048 * 2) + rnd((size_t)3 * CH * 512 * 4) +
           3 * rnd((size_t)2 * CH * LP * 512 * 2);
  };
  const size_t lgbytes = rnd((size_t)LP * LP * 4);
  int CH = 8;
  while (CH > 1 && persist + chpart(CH) + lgbytes > ws_size) CH >>= 1;
  if (persist + chpart(CH) + lgbytes > ws_size) return;
  int NA = (int)((ws_size - persist - chpart(CH)) / lgbytes);
  if (NA > 2 * CH) NA = 2 * CH;
  int nc = 8 / CH;

  char* w = (char*)d_ws;
  auto alloc = [&](size_t bytes) { char* p = w; w += (bytes + 255) / 256 * 256; return p; };
  float* embz = (float*)alloc((size_t)LP * 512 * 4);
  short* xbf  = (short*)alloc((size_t)Bb * Ll * 512 * 2);
  short* wpxT = (short*)alloc((size_t)512 * 2048 * 2);
  short* wpqT = (short*)alloc((size_t)512 * 2048 * 2);
  short* wpkT = (short*)alloc((size_t)512 * 2048 * 2);
  short* wpvT = (short*)alloc((size_t)512 * 2048 * 2);
  short* WqT  = (short*)alloc((size_t)8 * 512 * 512 * 2);
  short* WkT  = (short*)alloc((size_t)8 * 512 * 512 * 2);
  short* WvT  = (short*)alloc((size_t)8 * 512 * 512 * 2);
  short* WdB  = (short*)alloc((size_t)512 * 4096 * 2);
  short* Outb = (short*)alloc((size_t)16 * LP * 512 * 2);
  short* PX   = (short*)alloc((size_t)2 * LP * 512 * 2);
  float* Y    = (float*)alloc((size_t)2 * LL2 * 512 * 4);
  float* cfx  = (float*)alloc((size_t)16 * LP * 4);
  short* Weff = (short*)alloc((size_t)3 * CH * 512 * 2048 * 2);
  float* beff = (float*)alloc((size_t)3 * CH * 512 * 4);
  short* PQ   = (short*)alloc((size_t)2 * CH * LP * 512 * 2);
  short* PKf  = (short*)alloc((size_t)2 * CH * LP * 512 * 2);
  short* PVt  = (short*)alloc((size_t)2 * CH * LP * 512 * 2);
  float* Lg   = (float*)alloc((size_t)NA * LP * LP * 4);

  dim3 blk(256);
  emb_kernel<<<dim3((LP * 512 + 255) / 256), blk, 0, stream>>>(embz);
  cvt_kernel<<<dim3((Bb * Ll * 512 / 4 + 255) / 256), blk, 0, stream>>>(x, xbf, Bb * Ll * 512 / 4);
  wpxt_kernel<<<dim3(4096), blk, 0, stream>>>(wpx, wpxT);
  wpxt_kernel<<<dim3(4096), blk, 0, stream>>>(wpq, wpqT);
  wpxt_kernel<<<dim3(4096), blk, 0, stream>>>(wpk, wpkT);
  wpxt_kernel<<<dim3(4096), blk, 0, stream>>>(wpv, wpvT);
  tr_w_kernel<<<dim3(8, 8, 8), blk, 0, stream>>>(Wq, WqT);
  tr_w_kernel<<<dim3(8, 8, 8), blk, 0, stream>>>(Wk, WkT);
  tr_w_kernel<<<dim3(8, 8, 8), blk, 0, stream>>>(Wv, WvT);
  cvt_kernel<<<dim3((512 * 4096 / 4 + 255) / 256), blk, 0, stream>>>(Wd, WdB, 512 * 4096 / 4);
  pxcls_kernel<<<dim3(2), dim3(512), 0, stream>>>(x, PX);

  for (int c = 0; c < nc; ++c) {
    int h0 = c * CH;
    weff128<<<dim3(4, 4, 12 * CH), blk, 0, stream>>>(wpqT, wpkT, wpvT, WqT, WkT, WvT,
                                                     h0, CH, Weff);
    beff_fused<<<dim3(3, CH, 4), blk, 0, stream>>>(bq, bk, bv, wpq, wpk, wpv, h0, CH, beff);
    pool128x2<<<dim3(13 * (12 * CH + 4)), blk, 0, stream>>>(xbf, Weff, wpxT, beff, embz,
                                                            PQ, PKf, PVt, PX, CH);
    cls_fast<<<dim3(128, 3, 2 * CH), blk, 0, stream>>>(xbf, Wq, bq, Wk, bk, Wv, bv,
                                                       h0, CH, PQ, PKf, PVt);
    for (int a0 = 0; a0 < 2 * CH; a0 += NA) {
      int na = (2 * CH - a0) < NA ? (2 * CH - a0) : NA;
      cfix_kernel<<<dim3(400, na), blk, 0, stream>>>(PQ, embz, a0, cfx);
      logits128<<<dim3(13, 13, na), blk, 0, stream>>>(PQ, PKf, cfx, a0, Lg);
      softmax_kernel<<<dim3((LL2 + 3) / 4, na), blk, 0, stream>>>(Lg);
      av128<<<dim3(13, 4, na), blk, 0, stream>>>(Lg, PVt, PQ, Outb, h0, CH, a0);
    }
  }

  final128<<<dim3(25, 4), blk, 0, stream>>>(Outb, WdB, bd, PX, Y);
  ln_kernel<<<dim3(Bb * LL2), blk, 0, stream>>>(Y, gamma, beta, outp);
}

// Round 12
// 865.854 us; speedup vs baseline: 1.1633x; 1.0969x over previous
//
#include <hip/hip_runtime.h>
#include <hip/hip_bf16.h>
#include <cstdint>
#include <cstddef>

typedef __hip_bfloat16 bf16;
typedef __attribute__((ext_vector_type(8))) short short8;   // 8 bf16 in 4 VGPRs
typedef __attribute__((ext_vector_type(4))) short short4v;
typedef __attribute__((ext_vector_type(4))) float f32x4;
#define DEVI __device__ __forceinline__

constexpr int Bb = 2, Ll = 6273, Pp = 1568, LL2 = 1569, LP = 1600;
constexpr float QK_SCALE = 0.04419417382415922f;  // 512^-0.5

DEVI short f2bs(float f) {
  __hip_bfloat16 h = __float2bfloat16(f);
  return __builtin_bit_cast(short, h);
}
DEVI float bs2f(short s) {
  __hip_bfloat16 h = __builtin_bit_cast(__hip_bfloat16, s);
  return __bfloat162float(h);
}

// async global->LDS, 16B per lane. LDS dest = wave-uniform base + lane*16.
DEVI void gload16(const short* g, short* l) {
  __builtin_amdgcn_global_load_lds(
      (const __attribute__((address_space(1))) void*)g,
      (__attribute__((address_space(3))) void*)l,
      16, 0, 0);
}

// ===========================================================================
// 128x128 MFMA tile cores, BK=64, 256 threads = 4 waves in 2x2.
// PROVEN schedule: single-buffer stage -> sync -> mma -> sync (R1).
// Register ledger (R5-R8) + occupancy ledger (R10, settled):
//  - no __launch_bounds__ => 128-reg cap => wide acc spills (R5/R6).
//  - __launch_bounds__(256) uncapped => 280 regs => 1 blk/CU (R7).
//  - __launch_bounds__(256,2) + b-shared mma128_dual => 224 regs/wave,
//    2 waves/SIMD, no spill (R8) — pays ONLY where B streams from HBM and
//    K is long (pool). R10: on L2-resident-B short-K kernels it LOSES.
// R12: Lg stored as bf16 end-to-end (halves logits-write + softmax-read
// streams, ~160MB saved); exp/sum still f32.
// 16B-slot XOR swizzle (slot ^= row&7) -> conflict-free b128 reads.
// Staging: global_load_lds LINEAR dest + inverse-swizzled per-lane global
// SOURCE (rule 21). C/D layout per m89: col=lane&15, row=quad*4+e.
// ===========================================================================
constexpr int BK = 64;

DEVI int sw_idx(int row, int slot) {            // slot = 16B unit (8 shorts)
  return row * BK + (((slot) ^ (row & 7)) << 3);
}

DEVI void mma128(const short* As, const short* Bs, int lane, int wr, int wc,
                 f32x4 (&acc)[4][4]) {
  int m = lane & 15, quad = lane >> 4;
  #pragma unroll
  for (int kh = 0; kh < 2; ++kh) {
    int slot = kh * 4 + quad;
    short8 a[4], b[4];
    #pragma unroll
    for (int i = 0; i < 4; ++i) {
      int row = wr * 64 + i * 16 + m;
      a[i] = *(const short8*)(As + sw_idx(row, slot));
    }
    #pragma unroll
    for (int j = 0; j < 4; ++j) {
      int row = wc * 64 + j * 16 + m;
      b[j] = *(const short8*)(Bs + sw_idx(row, slot));
    }
    #pragma unroll
    for (int i = 0; i < 4; ++i)
      #pragma unroll
      for (int j = 0; j < 4; ++j)
        acc[i][j] = __builtin_amdgcn_mfma_f32_16x16x32_bf16(a[i], b[j], acc[i][j], 0, 0, 0);
  }
}

// Dual-A core: loads shared b[4] ONCE for two A-tiles (pool only).
DEVI void mma128_dual(const short* As0, const short* As1, const short* Bs,
                      int lane, int wr, int wc,
                      f32x4 (&acc0)[4][4], f32x4 (&acc1)[4][4]) {
  int m = lane & 15, quad = lane >> 4;
  #pragma unroll
  for (int kh = 0; kh < 2; ++kh) {
    int slot = kh * 4 + quad;
    short8 b[4];
    #pragma unroll
    for (int j = 0; j < 4; ++j)
      b[j] = *(const short8*)(Bs + sw_idx(wc * 64 + j * 16 + m, slot));
    #pragma unroll
    for (int i = 0; i < 4; ++i) {
      int row = wr * 64 + i * 16 + m;
      short8 a0 = *(const short8*)(As0 + sw_idx(row, slot));
      short8 a1 = *(const short8*)(As1 + sw_idx(row, slot));
      #pragma unroll
      for (int j = 0; j < 4; ++j) {
        acc0[i][j] = __builtin_amdgcn_mfma_f32_16x16x32_bf16(a0, b[j], acc0[i][j], 0, 0, 0);
        acc1[i][j] = __builtin_amdgcn_mfma_f32_16x16x32_bf16(a1, b[j], acc1[i][j], 0, 0, 0);
      }
    }
  }
}

// ---------------------------------------------------------------------------
__global__ void emb_kernel(float* __restrict__ embz) {
  int idx = blockIdx.x * 256 + threadIdx.x;
  if (idx >= LP * 512) return;
  int p = idx >> 9, d = idx & 511;
  float v = 0.f;
  if (p > 0 && p < LL2) {
    int pb = p - 1;
    int t = pb / 196, r = pb % 196;
    int h = r / 14, ww = r % 14;
    int pos, j, half;
    if (d < 170)      { pos = t;  j = d;       half = 85; }
    else if (d < 340) { pos = h;  j = d - 170; half = 85; }
    else              { pos = ww; j = d - 340; half = 86; }
    int jj = (j < half) ? j : (j - half);
    float omega = powf(10000.f, -(float)jj / (float)half);
    float ang = (float)pos * omega;
    v = (j < half) ? sinf(ang) : cosf(ang);
  }
  embz[idx] = v;
}

// f32 -> bf16 bulk convert, 4 elements/thread
__global__ void cvt_kernel(const float* __restrict__ src, short* __restrict__ dst, int n4) {
  int idx = blockIdx.x * 256 + threadIdx.x;
  if (idx >= n4) return;
  float4 v = *(const float4*)(src + (size_t)idx * 4);
  short4v o = { f2bs(v.x), f2bs(v.y), f2bs(v.z), f2bs(v.w) };
  *(short4v*)(dst + (size_t)idx * 4) = o;
}

// wpT[n][tap*512+k] = bf16(wp[n*2048 + k*4 + tap])  (works for wpx/wpq/wpk/wpv)
__global__ void wpxt_kernel(const float* __restrict__ wp, short* __restrict__ wpT) {
  int idx = blockIdx.x * 256 + threadIdx.x;
  if (idx >= 512 * 2048) return;
  int n = idx >> 11, rem = idx & 2047, tap = rem >> 9, k = rem & 511;
  wpT[idx] = f2bs(wp[n * 2048 + k * 4 + tap]);
}

// WT[h][k][i] = bf16(W[(h*512+i)*512 + k])
__global__ void tr_w_kernel(const float* __restrict__ W, short* __restrict__ WT) {
  __shared__ float Ws[64][65];
  int i0 = blockIdx.x * 64, k0 = blockIdx.y * 64, h = blockIdx.z;
  int tid = threadIdx.x;
  int r = tid >> 2, c0 = (tid & 3) * 16;
  const float* src = W + ((size_t)(h * 512 + i0 + r)) * 512 + k0 + c0;
  #pragma unroll
  for (int j = 0; j < 16; ++j) Ws[r][c0 + j] = src[j];
  __syncthreads();
  short* dst = WT + ((size_t)(h * 512 + k0 + r)) * 512 + i0 + c0;
  #pragma unroll
  for (int j = 0; j < 16; ++j) dst[j] = f2bs(Ws[c0 + j][r]);
}

// ===========================================================================
// weff128: grid (4, 4, 12*CH) — R1 single-buffer schedule, high occupancy.
// ===========================================================================
__global__ void weff128(const short* __restrict__ wpqT, const short* __restrict__ wpkT,
                        const short* __restrict__ wpvT,
                        const short* __restrict__ WqT, const short* __restrict__ WkT,
                        const short* __restrict__ WvT,
                        int h0, int CH, short* __restrict__ Weff) {
  __shared__ __align__(16) short As[128 * BK];
  __shared__ __align__(16) short Bs[128 * BK];
  int n0 = blockIdx.x * 128, k0 = blockIdx.y * 128;
  int z = blockIdx.z;
  int mat = z / (4 * CH), rem = z % (4 * CH);
  int ch = rem >> 2, tap = rem & 3;
  const short* wpT = mat == 0 ? wpqT : (mat == 1 ? wpkT : wpvT);
  const short* WT  = mat == 0 ? WqT  : (mat == 1 ? WkT  : WvT);
  int h = h0 + ch;
  int tid = threadIdx.x, lane = tid & 63, w = tid >> 6, wr = w >> 1, wc = w & 1;
  int rbase = tid >> 3;
  int ss = ((tid & 7) ^ (rbase & 7)) << 3;   // pre-swizzled source slot (shorts)
  f32x4 acc[4][4] = {};
  for (int kq = 0; kq < 512; kq += BK) {
    #pragma unroll
    for (int p = 0; p < 4; ++p) {
      int row = rbase + 32 * p;
      gload16(wpT + (size_t)(n0 + row) * 2048 + tap * 512 + kq + ss,
              As + (32 * p + 8 * w) * BK);
      gload16(WT + ((size_t)(h * 512 + k0 + row)) * 512 + kq + ss,
              Bs + (32 * p + 8 * w) * BK);
    }
    __syncthreads();
    mma128(As, Bs, lane, wr, wc, acc);
    __syncthreads();
  }
  int m = lane & 15, quad = lane >> 4;
  size_t base = ((size_t)(mat * CH + ch) * 512) * 2048 + tap * 512;
  #pragma unroll
  for (int i = 0; i < 4; ++i)
    #pragma unroll
    for (int j = 0; j < 4; ++j)
      #pragma unroll
      for (int e = 0; e < 4; ++e) {
        int n = n0 + wr * 64 + i * 16 + quad * 4 + e;
        int k = k0 + wc * 64 + j * 16 + m;
        Weff[base + (size_t)n * 2048 + k] = f2bs(acc[i][j][e]);
      }
}

// beff[(mat*CH+ch)][n]: wave-per-n, coalesced (R9). grid (3, CH, 4).
__global__ void beff_fused(const float* __restrict__ bq, const float* __restrict__ bk,
                           const float* __restrict__ bv,
                           const float* __restrict__ wpq, const float* __restrict__ wpk,
                           const float* __restrict__ wpv,
                           int h0, int CH, float* __restrict__ beff) {
  int mat = blockIdx.x, ch = blockIdx.y, n0 = blockIdx.z * 128;
  int wv = threadIdx.x >> 6, lane = threadIdx.x & 63;
  const float* bias = mat == 0 ? bq : (mat == 1 ? bk : bv);
  const float* wp = mat == 0 ? wpq : (mat == 1 ? wpk : wpv);
  float bi[8];
  #pragma unroll
  for (int t = 0; t < 8; ++t) bi[t] = bias[(h0 + ch) * 512 + lane * 8 + t];
  for (int n = n0 + wv; n < n0 + 128; n += 4) {
    const float* row = wp + (size_t)n * 2048 + lane * 32;
    float s = 0.f;
    #pragma unroll
    for (int t = 0; t < 8; ++t) {
      float4 v = *(const float4*)(row + t * 4);
      s += bi[t] * (v.x + v.y + v.z + v.w);
    }
    #pragma unroll
    for (int off = 32; off; off >>= 1) s += __shfl_down(s, off, 64);
    if (lane == 0) beff[(mat * CH + ch) * 512 + n] = s;
  }
}

// ===========================================================================
// pool128x2: one B-tile shared by TWO A-tiles; PX folded as mat==3 (R9).
// __launch_bounds__(256,2): 96 VGPR + 128 AGPR, 2 waves/SIMD, no spill (R8).
// grid 13*(12*CH+4), bijective XCD swizzle (m204).
// ===========================================================================
__global__ void __launch_bounds__(256, 2)
pool128x2(const short* __restrict__ xbf, const short* __restrict__ Weff,
          const short* __restrict__ wpxT,
          const float* __restrict__ beff, const float* __restrict__ embz,
          short* __restrict__ PQ, short* __restrict__ PKf,
          short* __restrict__ PVt, short* __restrict__ PX, int CH) {
  int NT = 12 * CH + 4;
  int nwg = 13 * NT;
  int bid = blockIdx.x;
  int q8 = nwg >> 3, r8 = nwg & 7;
  int xcd = bid & 7, lin = bid >> 3;
  int wgid = (xcd < r8 ? xcd * (q8 + 1) : r8 * (q8 + 1) + (xcd - r8) * q8) + lin;
  int nt = wgid % NT, pr = wgid / NT;
  int mb0 = pr * 2, mb1 = pr * 2 + 1;
  int mt0 = mb0 % 13, b0 = mb0 / 13;
  int mt1 = mb1 % 13, b1 = mb1 / 13;
  int mat, ch, n0t;
  const short* Bsrc;
  if (nt < 12 * CH) {
    mat = nt / (4 * CH); ch = (nt >> 2) % CH; n0t = (nt & 3) * 128;
    Bsrc = Weff + (size_t)nt * 128 * 2048;
  } else {
    mat = 3; ch = 0; n0t = (nt - 12 * CH) * 128;
    Bsrc = wpxT + (size_t)n0t * 2048;
  }

  __shared__ __align__(16) short As0[128 * BK];
  __shared__ __align__(16) short As1[128 * BK];
  __shared__ __align__(16) short Bs[128 * BK];
  int tid = threadIdx.x, lane = tid & 63, w = tid >> 6, wr = w >> 1, wc = w & 1;
  int rbase = tid >> 3;
  int ss = ((tid & 7) ^ (rbase & 7)) << 3;
  int srcA0[4], srcA1[4];
  #pragma unroll
  for (int p = 0; p < 4; ++p) {
    int row = rbase + 32 * p;
    int pb0 = mt0 * 128 + row; if (pb0 > Pp - 1) pb0 = Pp - 1;
    int t3 = pb0 / 196, rm = pb0 % 196, h2 = rm / 14, w2 = rm % 14;
    srcA0[p] = b0 * (Ll * 512) + (1 + t3 * 784 + h2 * 56 + w2 * 2) * 512;
    int pb1 = mt1 * 128 + row; if (pb1 > Pp - 1) pb1 = Pp - 1;
    int t3b = pb1 / 196, rmb = pb1 % 196, h2b = rmb / 14, w2b = rmb % 14;
    srcA1[p] = b1 * (Ll * 512) + (1 + t3b * 784 + h2b * 56 + w2b * 2) * 512;
  }

  f32x4 acc0[4][4] = {};
  f32x4 acc1[4][4] = {};
  for (int kq = 0; kq < 2048; kq += BK) {
    int tap = kq >> 9, koff = kq & 511;
    int tr = ((tap & 1) + (tap >> 1) * 28) * 512;
    #pragma unroll
    for (int p = 0; p < 4; ++p) {
      int row = rbase + 32 * p;
      gload16(xbf + (size_t)(srcA0[p] + tr + koff + ss), As0 + (32 * p + 8 * w) * BK);
      gload16(xbf + (size_t)(srcA1[p] + tr + koff + ss), As1 + (32 * p + 8 * w) * BK);
      gload16(Bsrc + (size_t)row * 2048 + kq + ss, Bs + (32 * p + 8 * w) * BK);
    }
    __syncthreads();
    mma128_dual(As0, As1, Bs, lane, wr, wc, acc0, acc1);
    __syncthreads();
  }
  int m = lane & 15, quad = lane >> 4;
  int bb = (mat < 3 ? (mat * CH + ch) : 0) * 512;
  {
    int cg = b0 * CH + ch;
    #pragma unroll
    for (int i = 0; i < 4; ++i)
      #pragma unroll
      for (int j = 0; j < 4; ++j)
        #pragma unroll
        for (int e = 0; e < 4; ++e) {
          int row = wr * 64 + i * 16 + quad * 4 + e;
          int pb = mt0 * 128 + row;
          if (pb >= Pp) continue;
          int tok = pb + 1;
          int n = n0t + wc * 64 + j * 16 + m;
          float bv = (mat < 3) ? beff[bb + n] : 0.f;
          float val = acc0[i][j][e] + bv;
          if (mat == 0)      PQ[((size_t)cg * LP + tok) * 512 + n] = f2bs(val);
          else if (mat == 1) PKf[((size_t)cg * LP + tok) * 512 + n] =
                                 f2bs(val * QK_SCALE + embz[(size_t)tok * 512 + n]);
          else if (mat == 2) PVt[((size_t)cg * 512 + n) * LP + tok] = f2bs(val);
          else               PX[((size_t)b0 * LP + tok) * 512 + n] = f2bs(val);
        }
  }
  {
    int cg = b1 * CH + ch;
    #pragma unroll
    for (int i = 0; i < 4; ++i)
      #pragma unroll
      for (int j = 0; j < 4; ++j)
        #pragma unroll
        for (int e = 0; e < 4; ++e) {
          int row = wr * 64 + i * 16 + quad * 4 + e;
          int pb = mt1 * 128 + row;
          if (pb >= Pp) continue;
          int tok = pb + 1;
          int n = n0t + wc * 64 + j * 16 + m;
          float bv = (mat < 3) ? beff[bb + n] : 0.f;
          float val = acc1[i][j][e] + bv;
          if (mat == 0)      PQ[((size_t)cg * LP + tok) * 512 + n] = f2bs(val);
          else if (mat == 1) PKf[((size_t)cg * LP + tok) * 512 + n] =
                                 f2bs(val * QK_SCALE + embz[(size_t)tok * 512 + n]);
          else if (mat == 2) PVt[((size_t)cg * 512 + n) * LP + tok] = f2bs(val);
          else               PX[((size_t)b1 * LP + tok) * 512 + n] = f2bs(val);
        }
  }
}

// cls row (token 0): one wave per output dot product. grid(128, 3, 2CH)
__global__ void cls_fast(const short* __restrict__ xbf,
                         const float* __restrict__ Wq, const float* __restrict__ bq,
                         const float* __restrict__ Wk, const float* __restrict__ bk,
                         const float* __restrict__ Wv, const float* __restrict__ bv,
                         int h0, int CH,
                         short* __restrict__ PQ, short* __restrict__ PKf,
                         short* __restrict__ PVt) {
  int cg = blockIdx.z, mat = blockIdx.y;
  int wv = threadIdx.x >> 6, lane = threadIdx.x & 63;
  int n = blockIdx.x * 4 + wv;
  int b = cg / CH, h = h0 + cg % CH;
  const float* W = mat == 0 ? Wq : (mat == 1 ? Wk : Wv);
  const float* bias = mat == 0 ? bq : (mat == 1 ? bk : bv);
  const short* xr = xbf + (size_t)b * Ll * 512;
  const float* wr = W + ((size_t)(h * 512 + n)) * 512;
  float s = 0.f;
  #pragma unroll
  for (int j = 0; j < 8; ++j) {
    int k = lane * 8 + j;
    s += bs2f(xr[k]) * wr[k];
  }
  #pragma unroll
  for (int off = 32; off; off >>= 1) s += __shfl_down(s, off, 64);
  if (lane == 0) {
    s += bias[h * 512 + n];
    if (mat == 0)      PQ[((size_t)cg * LP) * 512 + n] = f2bs(s);
    else if (mat == 1) PKf[((size_t)cg * LP) * 512 + n] = f2bs(s * QK_SCALE);
    else               PVt[((size_t)cg * 512 + n) * LP] = f2bs(s);
  }
}

// PX cls row
__global__ void pxcls_kernel(const float* __restrict__ x, short* __restrict__ PX) {
  int b = blockIdx.x, n = threadIdx.x;
  PX[(size_t)b * LP * 512 + n] = f2bs(x[(size_t)b * Ll * 512 + n]);
}

// cfx[cg][kt] = dot(PQ[cg,0,:], embz[kt,:])
__global__ void cfix_kernel(const short* __restrict__ PQ, const float* __restrict__ embz,
                            int a0, float* __restrict__ cfx) {
  int cg = a0 + blockIdx.y;
  int wv = threadIdx.x >> 6, lane = threadIdx.x & 63;
  int kt = blockIdx.x * 4 + wv;
  if (kt >= LP) return;
  int ktc = kt < LL2 ? kt : (LL2 - 1);
  const short* q0 = PQ + (size_t)cg * LP * 512;
  const float* e = embz + (size_t)ktc * 512;
  float s = 0.f;
  #pragma unroll
  for (int j = 0; j < 8; ++j) {
    int d = lane * 8 + j;
    s += bs2f(q0[d]) * e[d];
  }
  #pragma unroll
  for (int off = 32; off; off >>= 1) s += __shfl_down(s, off, 64);
  if (lane == 0) cfx[(size_t)cg * LP + kt] = s;
}

// ===========================================================================
// logits128: Lg[z][q][kt] (bf16) = PQ[cg] . PKf[cg]; row0 -= cfx. grid (13,13,na)
// ===========================================================================
__global__ void logits128(const short* __restrict__ PQ, const short* __restrict__ PKf,
                          const float* __restrict__ cfx, int a0, short* __restrict__ Lg) {
  __shared__ __align__(16) short As[128 * BK];
  __shared__ __align__(16) short Bs[128 * BK];
  int q0 = blockIdx.x * 128, k0 = blockIdx.y * 128, z = blockIdx.z;
  int cg = a0 + z;
  int tid = threadIdx.x, lane = tid & 63, w = tid >> 6, wr = w >> 1, wc = w & 1;
  int rbase = tid >> 3;
  int ss = ((tid & 7) ^ (rbase & 7)) << 3;
  const short* Aq = PQ + (size_t)cg * LP * 512;
  const short* Bk = PKf + (size_t)cg * LP * 512;
  f32x4 acc[4][4] = {};
  for (int kq = 0; kq < 512; kq += BK) {
    #pragma unroll
    for (int p = 0; p < 4; ++p) {
      int row = rbase + 32 * p;
      int ar = q0 + row; if (ar > LL2 - 1) ar = LL2 - 1;
      int br = k0 + row; if (br > LL2 - 1) br = LL2 - 1;
      gload16(Aq + (size_t)ar * 512 + kq + ss, As + (32 * p + 8 * w) * BK);
      gload16(Bk + (size_t)br * 512 + kq + ss, Bs + (32 * p + 8 * w) * BK);
    }
    __syncthreads();
    mma128(As, Bs, lane, wr, wc, acc);
    __syncthreads();
  }
  int m = lane & 15, quad = lane >> 4;
  short* lg = Lg + (size_t)z * LP * LP;
  const float* cf = cfx + (size_t)cg * LP;
  #pragma unroll
  for (int i = 0; i < 4; ++i)
    #pragma unroll
    for (int j = 0; j < 4; ++j)
      #pragma unroll
      for (int e = 0; e < 4; ++e) {
        int q = q0 + wr * 64 + i * 16 + quad * 4 + e;
        int kt = k0 + wc * 64 + j * 16 + m;
        if (q >= LP || kt >= LP) continue;
        float val = acc[i][j][e];
        if (q == 0) val -= cf[kt];
        lg[(size_t)q * LP + kt] = f2bs(val);
      }
}

// softmax: wave-per-row single-pass over bf16 logits (R12). 4 short8 loads,
// two shfl reductions, exp in f32, bf16 in-place store (zero-pad preserved).
// grid (ceil(LL2/4), na), 256 thr = 4 waves = 4 rows/block.
__global__ void softmax_kernel(short* __restrict__ Lg) {
  int z = blockIdx.y;
  int wv = threadIdx.x >> 6, lane = threadIdx.x & 63;
  int q = blockIdx.x * 4 + wv;
  if (q >= LL2) return;
  short* p = Lg + ((size_t)z * LP + q) * LP;
  float vbuf[32];
  float mx = -1e30f;
  #pragma unroll
  for (int it = 0; it < 4; ++it) {
    int j = it * 512 + lane * 8;
    short8 v = {0, 0, 0, 0, 0, 0, 0, 0};
    if (j < LP) v = *(const short8*)(p + j);
    #pragma unroll
    for (int e = 0; e < 8; ++e) {
      float f = bs2f(v[e]);
      float masked = (j < LP && (j + e) < LL2) ? f : -1e30f;
      vbuf[it * 8 + e] = masked;
      mx = fmaxf(mx, masked);
    }
  }
  #pragma unroll
  for (int off = 32; off; off >>= 1) mx = fmaxf(mx, __shfl_xor(mx, off, 64));
  float sum = 0.f;
  #pragma unroll
  for (int it = 0; it < 4; ++it)
    #pragma unroll
    for (int e = 0; e < 8; ++e) {
      float ev = __expf(vbuf[it * 8 + e] - mx);   // masked -> exp(-huge) = 0
      vbuf[it * 8 + e] = ev;
      sum += ev;
    }
  #pragma unroll
  for (int off = 32; off; off >>= 1) sum += __shfl_xor(sum, off, 64);
  float inv = 1.f / sum;
  #pragma unroll
  for (int it = 0; it < 4; ++it) {
    int j = it * 512 + lane * 8;
    if (j < LP) {
      short8 ov;
      #pragma unroll
      for (int e = 0; e < 8; ++e) ov[e] = f2bs(vbuf[it * 8 + e] * inv);
      *(short8*)(p + j) = ov;
    }
  }
}

// ===========================================================================
// av128: Outb[gg][q][n] = attn @ PVt + (q==0?1:2)*PQ. grid (13,4,na)
// A rows are bf16 at stride LP now.
// ===========================================================================
__global__ void av128(const short* __restrict__ Lg, const short* __restrict__ PVt,
                      const short* __restrict__ PQ, short* __restrict__ Outb,
                      int h0, int CH, int a0) {
  __shared__ __align__(16) short As[128 * BK];
  __shared__ __align__(16) short Bs[128 * BK];
  int q0 = blockIdx.x * 128, n0 = blockIdx.y * 128, z = blockIdx.z;
  int cg = a0 + z;
  int b = cg / CH, gg = b * 8 + h0 + cg % CH;
  int tid = threadIdx.x, lane = tid & 63, w = tid >> 6, wr = w >> 1, wc = w & 1;
  int rbase = tid >> 3;
  int ss = ((tid & 7) ^ (rbase & 7)) << 3;
  const short* Aat = Lg + (size_t)z * LP * LP;   // bf16 rows, stride LP
  const short* Bv = PVt + (size_t)cg * 512 * LP;
  f32x4 acc[4][4] = {};
  for (int kq = 0; kq < LP; kq += BK) {
    #pragma unroll
    for (int p = 0; p < 4; ++p) {
      int row = rbase + 32 * p;
      int ar = q0 + row; if (ar > LP - 1) ar = LP - 1;
      gload16(Aat + (size_t)ar * LP + kq + ss, As + (32 * p + 8 * w) * BK);
      gload16(Bv + (size_t)(n0 + row) * LP + kq + ss, Bs + (32 * p + 8 * w) * BK);
    }
    __syncthreads();
    mma128(As, Bs, lane, wr, wc, acc);
    __syncthreads();
  }
  int m = lane & 15, quad = lane >> 4;
  #pragma unroll
  for (int i = 0; i < 4; ++i)
    #pragma unroll
    for (int j = 0; j < 4; ++j)
      #pragma unroll
      for (int e = 0; e < 4; ++e) {
        int q = q0 + wr * 64 + i * 16 + quad * 4 + e;
        if (q >= LL2) continue;
        int n = n0 + wc * 64 + j * 16 + m;
        float res = bs2f(PQ[((size_t)cg * LP + q) * 512 + n]);
        float val = acc[i][j][e] + (q == 0 ? 1.f : 2.f) * res;
        Outb[((size_t)gg * LP + q) * 512 + n] = f2bs(val);
      }
}

// ===========================================================================
// final128: Y = stacked @ Wd^T + bd + PX. grid (25, 4). M=3138 flat (b,q).
// ===========================================================================
__global__ void final128(const short* __restrict__ Outb, const short* __restrict__ WdB,
                         const float* __restrict__ bd, const short* __restrict__ PX,
                         float* __restrict__ Y) {
  __shared__ __align__(16) short As[128 * BK];
  __shared__ __align__(16) short Bs[128 * BK];
  int mf0 = blockIdx.x * 128, n0 = blockIdx.y * 128;
  int tid = threadIdx.x, lane = tid & 63, w = tid >> 6, wr = w >> 1, wc = w & 1;
  int rbase = tid >> 3;
  int ss = ((tid & 7) ^ (rbase & 7)) << 3;
  const int M = Bb * LL2;  // 3138
  int brow[4], qrow[4];
  #pragma unroll
  for (int p = 0; p < 4; ++p) {
    int mf = mf0 + rbase + 32 * p; if (mf > M - 1) mf = M - 1;
    brow[p] = mf / LL2; qrow[p] = mf % LL2;
  }
  f32x4 acc[4][4] = {};
  for (int kq = 0; kq < 4096; kq += BK) {
    int hh = kq >> 9, koff = kq & 511;
    #pragma unroll
    for (int p = 0; p < 4; ++p) {
      int row = rbase + 32 * p;
      gload16(Outb + ((size_t)(brow[p] * 8 + hh) * LP + qrow[p]) * 512 + koff + ss,
              As + (32 * p + 8 * w) * BK);
      gload16(WdB + (size_t)(n0 + row) * 4096 + kq + ss,
              Bs + (32 * p + 8 * w) * BK);
    }
    __syncthreads();
    mma128(As, Bs, lane, wr, wc, acc);
    __syncthreads();
  }
  int m = lane & 15, quad = lane >> 4;
  #pragma unroll
  for (int i = 0; i < 4; ++i)
    #pragma unroll
    for (int j = 0; j < 4; ++j)
      #pragma unroll
      for (int e = 0; e < 4; ++e) {
        int mf = mf0 + wr * 64 + i * 16 + quad * 4 + e;
        if (mf >= M) continue;
        int b2 = mf / LL2, q2 = mf % LL2;
        int dm = n0 + wc * 64 + j * 16 + m;
        float val = acc[i][j][e] + bd[dm] + bs2f(PX[((size_t)b2 * LP + q2) * 512 + dm]);
        Y[(size_t)mf * 512 + dm] = val;
      }
}

// LayerNorm over 512
__global__ void ln_kernel(const float* __restrict__ Y, const float* __restrict__ gamma,
                          const float* __restrict__ beta, float* __restrict__ Outp) {
  int row = blockIdx.x;
  const float* y = Y + (size_t)row * 512;
  __shared__ float red[256];
  int tid = threadIdx.x;
  float v0 = y[tid], v1 = y[tid + 256];
  red[tid] = v0 + v1; __syncthreads();
  for (int s = 128; s; s >>= 1) { if (tid < s) red[tid] += red[tid + s]; __syncthreads(); }
  float mu = red[0] * (1.f / 512.f);
  __syncthreads();
  float d0 = v0 - mu, d1 = v1 - mu;
  red[tid] = d0 * d0 + d1 * d1; __syncthreads();
  for (int s = 128; s; s >>= 1) { if (tid < s) red[tid] += red[tid + s]; __syncthreads(); }
  float rstd = rsqrtf(red[0] * (1.f / 512.f) + 1e-5f);
  float* o = Outp + (size_t)row * 512;
  o[tid]       = d0 * rstd * gamma[tid]       + beta[tid];
  o[tid + 256] = d1 * rstd * gamma[tid + 256] + beta[tid + 256];
}

// ---------------------------------------------------------------------------
extern "C" void kernel_launch(void* const* d_in, const int* in_sizes, int n_in,
                              void* d_out, int out_size, void* d_ws, size_t ws_size,
                              hipStream_t stream) {
  const float* x     = (const float*)d_in[0];
  const float* Wq    = (const float*)d_in[1];
  const float* bq    = (const float*)d_in[2];
  const float* Wk    = (const float*)d_in[3];
  const float* bk    = (const float*)d_in[4];
  const float* Wv    = (const float*)d_in[5];
  const float* bv    = (const float*)d_in[6];
  const float* wpq   = (const float*)d_in[7];
  const float* wpk   = (const float*)d_in[8];
  const float* wpv   = (const float*)d_in[9];
  const float* wpx   = (const float*)d_in[10];
  const float* Wd    = (const float*)d_in[11];
  const float* bd    = (const float*)d_in[12];
  const float* gamma = (const float*)d_in[13];
  const float* beta  = (const float*)d_in[14];
  float* outp = (float*)d_out;

  auto rnd = [](size_t b) { return (b + 255) / 256 * 256; };
  const size_t persist =
      rnd((size_t)LP * 512 * 4) +            // embz
      rnd((size_t)Bb * Ll * 512 * 2) +       // xbf
      4 * rnd((size_t)512 * 2048 * 2) +      // wpxT + wpqT/wpkT/wpvT
      3 * rnd((size_t)8 * 512 * 512 * 2) +   // WqT/WkT/WvT
      rnd((size_t)512 * 4096 * 2) +          // WdB
      rnd((size_t)16 * LP * 512 * 2) +       // Outb
      rnd((size_t)2 * LP * 512 * 2) +        // PX
      rnd((size_t)2 * LL2 * 512 * 4) +       // Y
      rnd((size_t)16 * LP * 4);              // cfx
  auto chpart = [&](int CH) {
    return rnd((size_t)3 * CH * 512 * 2048 * 2) + rnd((size_t)3 * CH * 512 * 4) +
           3 * rnd((size_t)2 * CH * LP * 512 * 2);
  };
  const size_t lgbytes = rnd((size_t)LP * LP * 2);   // bf16 Lg (R12)
  int CH = 8;
  while (CH > 1 && persist + chpart(CH) + lgbytes > ws_size) CH >>= 1;
  if (persist + chpart(CH) + lgbytes > ws_size) return;
  int NA = (int)((ws_size - persist - chpart(CH)) / lgbytes);
  if (NA > 2 * CH) NA = 2 * CH;
  int nc = 8 / CH;

  char* w = (char*)d_ws;
  auto alloc = [&](size_t bytes) { char* p = w; w += (bytes + 255) / 256 * 256; return p; };
  float* embz = (float*)alloc((size_t)LP * 512 * 4);
  short* xbf  = (short*)alloc((size_t)Bb * Ll * 512 * 2);
  short* wpxT = (short*)alloc((size_t)512 * 2048 * 2);
  short* wpqT = (short*)alloc((size_t)512 * 2048 * 2);
  short* wpkT = (short*)alloc((size_t)512 * 2048 * 2);
  short* wpvT = (short*)alloc((size_t)512 * 2048 * 2);
  short* WqT  = (short*)alloc((size_t)8 * 512 * 512 * 2);
  short* WkT  = (short*)alloc((size_t)8 * 512 * 512 * 2);
  short* WvT  = (short*)alloc((size_t)8 * 512 * 512 * 2);
  short* WdB  = (short*)alloc((size_t)512 * 4096 * 2);
  short* Outb = (short*)alloc((size_t)16 * LP * 512 * 2);
  short* PX   = (short*)alloc((size_t)2 * LP * 512 * 2);
  float* Y    = (float*)alloc((size_t)2 * LL2 * 512 * 4);
  float* cfx  = (float*)alloc((size_t)16 * LP * 4);
  short* Weff = (short*)alloc((size_t)3 * CH * 512 * 2048 * 2);
  float* beff = (float*)alloc((size_t)3 * CH * 512 * 4);
  short* PQ   = (short*)alloc((size_t)2 * CH * LP * 512 * 2);
  short* PKf  = (short*)alloc((size_t)2 * CH * LP * 512 * 2);
  short* PVt  = (short*)alloc((size_t)2 * CH * LP * 512 * 2);
  short* Lg   = (short*)alloc((size_t)NA * LP * LP * 2);

  dim3 blk(256);
  emb_kernel<<<dim3((LP * 512 + 255) / 256), blk, 0, stream>>>(embz);
  cvt_kernel<<<dim3((Bb * Ll * 512 / 4 + 255) / 256), blk, 0, stream>>>(x, xbf, Bb * Ll * 512 / 4);
  wpxt_kernel<<<dim3(4096), blk, 0, stream>>>(wpx, wpxT);
  wpxt_kernel<<<dim3(4096), blk, 0, stream>>>(wpq, wpqT);
  wpxt_kernel<<<dim3(4096), blk, 0, stream>>>(wpk, wpkT);
  wpxt_kernel<<<dim3(4096), blk, 0, stream>>>(wpv, wpvT);
  tr_w_kernel<<<dim3(8, 8, 8), blk, 0, stream>>>(Wq, WqT);
  tr_w_kernel<<<dim3(8, 8, 8), blk, 0, stream>>>(Wk, WkT);
  tr_w_kernel<<<dim3(8, 8, 8), blk, 0, stream>>>(Wv, WvT);
  cvt_kernel<<<dim3((512 * 4096 / 4 + 255) / 256), blk, 0, stream>>>(Wd, WdB, 512 * 4096 / 4);
  pxcls_kernel<<<dim3(2), dim3(512), 0, stream>>>(x, PX);

  for (int c = 0; c < nc; ++c) {
    int h0 = c * CH;
    weff128<<<dim3(4, 4, 12 * CH), blk, 0, stream>>>(wpqT, wpkT, wpvT, WqT, WkT, WvT,
                                                     h0, CH, Weff);
    beff_fused<<<dim3(3, CH, 4), blk, 0, stream>>>(bq, bk, bv, wpq, wpk, wpv, h0, CH, beff);
    pool128x2<<<dim3(13 * (12 * CH + 4)), blk, 0, stream>>>(xbf, Weff, wpxT, beff, embz,
                                                            PQ, PKf, PVt, PX, CH);
    cls_fast<<<dim3(128, 3, 2 * CH), blk, 0, stream>>>(xbf, Wq, bq, Wk, bk, Wv, bv,
                                                       h0, CH, PQ, PKf, PVt);
    for (int a0 = 0; a0 < 2 * CH; a0 += NA) {
      int na = (2 * CH - a0) < NA ? (2 * CH - a0) : NA;
      cfix_kernel<<<dim3(400, na), blk, 0, stream>>>(PQ, embz, a0, cfx);
      logits128<<<dim3(13, 13, na), blk, 0, stream>>>(PQ, PKf, cfx, a0, Lg);
      softmax_kernel<<<dim3((LL2 + 3) / 4, na), blk, 0, stream>>>(Lg);
      av128<<<dim3(13, 4, na), blk, 0, stream>>>(Lg, PVt, PQ, Outb, h0, CH, a0);
    }
  }

  final128<<<dim3(25, 4), blk, 0, stream>>>(Outb, WdB, bd, PX, Y);
  ln_kernel<<<dim3(Bb * LL2), blk, 0, stream>>>(Y, gamma, beta, outp);
}

// Round 13
// 835.906 us; speedup vs baseline: 1.2050x; 1.0358x over previous
//
#include <hip/hip_runtime.h>
#include <hip/hip_bf16.h>
#include <cstdint>
#include <cstddef>

typedef __hip_bfloat16 bf16;
typedef __attribute__((ext_vector_type(8))) short short8;   // 8 bf16 in 4 VGPRs
typedef __attribute__((ext_vector_type(4))) short short4v;
typedef __attribute__((ext_vector_type(4))) float f32x4;
#define DEVI __device__ __forceinline__

constexpr int Bb = 2, Ll = 6273, Pp = 1568, LL2 = 1569, LP = 1600;
constexpr float QK_SCALE = 0.04419417382415922f;  // 512^-0.5

DEVI short f2bs(float f) {
  __hip_bfloat16 h = __float2bfloat16(f);
  return __builtin_bit_cast(short, h);
}
DEVI float bs2f(short s) {
  __hip_bfloat16 h = __builtin_bit_cast(__hip_bfloat16, s);
  return __bfloat162float(h);
}

// async global->LDS, 16B per lane. LDS dest = wave-uniform base + lane*16.
DEVI void gload16(const short* g, short* l) {
  __builtin_amdgcn_global_load_lds(
      (const __attribute__((address_space(1))) void*)g,
      (__attribute__((address_space(3))) void*)l,
      16, 0, 0);
}

// ===========================================================================
// MFMA tile cores, BK=64. PROVEN schedule: stage -> sync -> mma -> sync (R1).
// Ledger (R5-R12, settled):
//  - no __launch_bounds__ => 128-reg cap; >128 demand spills (R5/R6).
//  - 224 regs/wave (dual-acc) => 2 waves/SIMD: pays only for HBM-streaming-B
//    long-K (pool128x2, R8); loses on L2-resident short-K (R10).
//  - R13: pool512 = 128x256 tile, 512thr/8 waves, per-wave 64x64 (EXACT R1
//    per-wave register shape: ~120 regs) + __launch_bounds__(512,4) caps at
//    128 => 2 blocks/CU = 16 waves/CU, double pool128x2's TLP at equal
//    staging traffic (A shared by 4 wc-waves, B shared by 2 wr-waves).
//  - R12: Lg bf16 end-to-end.
// 16B-slot XOR swizzle (slot ^= row&7) -> conflict-free b128 reads.
// Staging: global_load_lds LINEAR dest + inverse-swizzled per-lane global
// SOURCE (rule 21). C/D layout per m89: col=lane&15, row=quad*4+e.
// ===========================================================================
constexpr int BK = 64;

DEVI int sw_idx(int row, int slot) {            // slot = 16B unit (8 shorts)
  return row * BK + (((slot) ^ (row & 7)) << 3);
}

// wr selects 64-row A block, wc selects 64-row B block (B may have >128 rows).
DEVI void mma128(const short* As, const short* Bs, int lane, int wr, int wc,
                 f32x4 (&acc)[4][4]) {
  int m = lane & 15, quad = lane >> 4;
  #pragma unroll
  for (int kh = 0; kh < 2; ++kh) {
    int slot = kh * 4 + quad;
    short8 a[4], b[4];
    #pragma unroll
    for (int i = 0; i < 4; ++i) {
      int row = wr * 64 + i * 16 + m;
      a[i] = *(const short8*)(As + sw_idx(row, slot));
    }
    #pragma unroll
    for (int j = 0; j < 4; ++j) {
      int row = wc * 64 + j * 16 + m;
      b[j] = *(const short8*)(Bs + sw_idx(row, slot));
    }
    #pragma unroll
    for (int i = 0; i < 4; ++i)
      #pragma unroll
      for (int j = 0; j < 4; ++j)
        acc[i][j] = __builtin_amdgcn_mfma_f32_16x16x32_bf16(a[i], b[j], acc[i][j], 0, 0, 0);
  }
}

// ---------------------------------------------------------------------------
__global__ void emb_kernel(float* __restrict__ embz) {
  int idx = blockIdx.x * 256 + threadIdx.x;
  if (idx >= LP * 512) return;
  int p = idx >> 9, d = idx & 511;
  float v = 0.f;
  if (p > 0 && p < LL2) {
    int pb = p - 1;
    int t = pb / 196, r = pb % 196;
    int h = r / 14, ww = r % 14;
    int pos, j, half;
    if (d < 170)      { pos = t;  j = d;       half = 85; }
    else if (d < 340) { pos = h;  j = d - 170; half = 85; }
    else              { pos = ww; j = d - 340; half = 86; }
    int jj = (j < half) ? j : (j - half);
    float omega = powf(10000.f, -(float)jj / (float)half);
    float ang = (float)pos * omega;
    v = (j < half) ? sinf(ang) : cosf(ang);
  }
  embz[idx] = v;
}

// f32 -> bf16 bulk convert, 4 elements/thread
__global__ void cvt_kernel(const float* __restrict__ src, short* __restrict__ dst, int n4) {
  int idx = blockIdx.x * 256 + threadIdx.x;
  if (idx >= n4) return;
  float4 v = *(const float4*)(src + (size_t)idx * 4);
  short4v o = { f2bs(v.x), f2bs(v.y), f2bs(v.z), f2bs(v.w) };
  *(short4v*)(dst + (size_t)idx * 4) = o;
}

// wpT[n][tap*512+k] = bf16(wp[n*2048 + k*4 + tap])  (works for wpx/wpq/wpk/wpv)
__global__ void wpxt_kernel(const float* __restrict__ wp, short* __restrict__ wpT) {
  int idx = blockIdx.x * 256 + threadIdx.x;
  if (idx >= 512 * 2048) return;
  int n = idx >> 11, rem = idx & 2047, tap = rem >> 9, k = rem & 511;
  wpT[idx] = f2bs(wp[n * 2048 + k * 4 + tap]);
}

// WT[h][k][i] = bf16(W[(h*512+i)*512 + k])
__global__ void tr_w_kernel(const float* __restrict__ W, short* __restrict__ WT) {
  __shared__ float Ws[64][65];
  int i0 = blockIdx.x * 64, k0 = blockIdx.y * 64, h = blockIdx.z;
  int tid = threadIdx.x;
  int r = tid >> 2, c0 = (tid & 3) * 16;
  const float* src = W + ((size_t)(h * 512 + i0 + r)) * 512 + k0 + c0;
  #pragma unroll
  for (int j = 0; j < 16; ++j) Ws[r][c0 + j] = src[j];
  __syncthreads();
  short* dst = WT + ((size_t)(h * 512 + k0 + r)) * 512 + i0 + c0;
  #pragma unroll
  for (int j = 0; j < 16; ++j) dst[j] = f2bs(Ws[c0 + j][r]);
}

// ===========================================================================
// weff128: grid (4, 4, 12*CH) — R1 single-buffer schedule, high occupancy.
// ===========================================================================
__global__ void weff128(const short* __restrict__ wpqT, const short* __restrict__ wpkT,
                        const short* __restrict__ wpvT,
                        const short* __restrict__ WqT, const short* __restrict__ WkT,
                        const short* __restrict__ WvT,
                        int h0, int CH, short* __restrict__ Weff) {
  __shared__ __align__(16) short As[128 * BK];
  __shared__ __align__(16) short Bs[128 * BK];
  int n0 = blockIdx.x * 128, k0 = blockIdx.y * 128;
  int z = blockIdx.z;
  int mat = z / (4 * CH), rem = z % (4 * CH);
  int ch = rem >> 2, tap = rem & 3;
  const short* wpT = mat == 0 ? wpqT : (mat == 1 ? wpkT : wpvT);
  const short* WT  = mat == 0 ? WqT  : (mat == 1 ? WkT  : WvT);
  int h = h0 + ch;
  int tid = threadIdx.x, lane = tid & 63, w = tid >> 6, wr = w >> 1, wc = w & 1;
  int rbase = tid >> 3;
  int ss = ((tid & 7) ^ (rbase & 7)) << 3;   // pre-swizzled source slot (shorts)
  f32x4 acc[4][4] = {};
  for (int kq = 0; kq < 512; kq += BK) {
    #pragma unroll
    for (int p = 0; p < 4; ++p) {
      int row = rbase + 32 * p;
      gload16(wpT + (size_t)(n0 + row) * 2048 + tap * 512 + kq + ss,
              As + (32 * p + 8 * w) * BK);
      gload16(WT + ((size_t)(h * 512 + k0 + row)) * 512 + kq + ss,
              Bs + (32 * p + 8 * w) * BK);
    }
    __syncthreads();
    mma128(As, Bs, lane, wr, wc, acc);
    __syncthreads();
  }
  int m = lane & 15, quad = lane >> 4;
  size_t base = ((size_t)(mat * CH + ch) * 512) * 2048 + tap * 512;
  #pragma unroll
  for (int i = 0; i < 4; ++i)
    #pragma unroll
    for (int j = 0; j < 4; ++j)
      #pragma unroll
      for (int e = 0; e < 4; ++e) {
        int n = n0 + wr * 64 + i * 16 + quad * 4 + e;
        int k = k0 + wc * 64 + j * 16 + m;
        Weff[base + (size_t)n * 2048 + k] = f2bs(acc[i][j][e]);
      }
}

// beff[(mat*CH+ch)][n]: wave-per-n, coalesced (R9). grid (3, CH, 4).
__global__ void beff_fused(const float* __restrict__ bq, const float* __restrict__ bk,
                           const float* __restrict__ bv,
                           const float* __restrict__ wpq, const float* __restrict__ wpk,
                           const float* __restrict__ wpv,
                           int h0, int CH, float* __restrict__ beff) {
  int mat = blockIdx.x, ch = blockIdx.y, n0 = blockIdx.z * 128;
  int wv = threadIdx.x >> 6, lane = threadIdx.x & 63;
  const float* bias = mat == 0 ? bq : (mat == 1 ? bk : bv);
  const float* wp = mat == 0 ? wpq : (mat == 1 ? wpk : wpv);
  float bi[8];
  #pragma unroll
  for (int t = 0; t < 8; ++t) bi[t] = bias[(h0 + ch) * 512 + lane * 8 + t];
  for (int n = n0 + wv; n < n0 + 128; n += 4) {
    const float* row = wp + (size_t)n * 2048 + lane * 32;
    float s = 0.f;
    #pragma unroll
    for (int t = 0; t < 8; ++t) {
      float4 v = *(const float4*)(row + t * 4);
      s += bi[t] * (v.x + v.y + v.z + v.w);
    }
    #pragma unroll
    for (int off = 32; off; off >>= 1) s += __shfl_down(s, off, 64);
    if (lane == 0) beff[(mat * CH + ch) * 512 + n] = s;
  }
}

// ===========================================================================
// pool512: 128x256 tile, 512 threads = 8 waves (2 wr x 4 wc), per-wave 64x64
// (R1 register shape, ~120 regs). __launch_bounds__(512,4) caps 128 regs/wave
// => 2 blocks/CU = 16 waves/CU. LDS 48KB (A 128x64, B 256x64).
// PX folded as mat==3. NT = 6*CH + 2 tiles of 256 cols.
// grid 26*NT, bijective XCD swizzle (m204), nt-minor (A L2-reuse per XCD).
// ===========================================================================
__global__ void __launch_bounds__(512, 4)
pool512(const short* __restrict__ xbf, const short* __restrict__ Weff,
        const short* __restrict__ wpxT,
        const float* __restrict__ beff, const float* __restrict__ embz,
        short* __restrict__ PQ, short* __restrict__ PKf,
        short* __restrict__ PVt, short* __restrict__ PX, int CH) {
  int NT = 6 * CH + 2;
  int nwg = 26 * NT;
  int bid = blockIdx.x;
  int q8 = nwg >> 3, r8 = nwg & 7;
  int xcd = bid & 7, lin = bid >> 3;
  int wgid = (xcd < r8 ? xcd * (q8 + 1) : r8 * (q8 + 1) + (xcd - r8) * q8) + lin;
  int nt = wgid % NT, mb = wgid / NT;        // mb 0..25
  int mt = mb % 13, b = mb / 13;
  int mat, ch, nbase;                        // nbase: col offset within 512
  const short* Bsrc;                         // base of the 256-row B panel
  if (nt < 6 * CH) {
    mat = nt / (2 * CH);
    int rem = nt % (2 * CH);
    ch = rem >> 1;
    nbase = (rem & 1) * 256;
    Bsrc = Weff + ((size_t)(mat * CH + ch) * 512 + nbase) * 2048;
  } else {
    mat = 3; ch = 0; nbase = (nt - 6 * CH) * 256;
    Bsrc = wpxT + (size_t)nbase * 2048;
  }

  __shared__ __align__(16) short As[128 * BK];   // 16KB
  __shared__ __align__(16) short Bs[256 * BK];   // 32KB
  int tid = threadIdx.x, lane = tid & 63, w = tid >> 6;
  int wr = w >> 2, wc = w & 3;
  int rbase = tid >> 3;                          // 0..63
  int ss = ((tid & 7) ^ (rbase & 7)) << 3;
  // A source bases: pooled rows pb = mt*128 + rbase + 64*p  (p=0,1)
  int srcA[2];
  #pragma unroll
  for (int p = 0; p < 2; ++p) {
    int pb = mt * 128 + rbase + 64 * p; if (pb > Pp - 1) pb = Pp - 1;
    int t3 = pb / 196, rm = pb % 196, h2 = rm / 14, w2 = rm % 14;
    srcA[p] = b * (Ll * 512) + (1 + t3 * 784 + h2 * 56 + w2 * 2) * 512;
  }

  f32x4 acc[4][4] = {};
  for (int kq = 0; kq < 2048; kq += BK) {
    int tap = kq >> 9, koff = kq & 511;
    int tr = ((tap & 1) + (tap >> 1) * 28) * 512;   // taprow {0,1,28,29} shorts
    #pragma unroll
    for (int p = 0; p < 2; ++p)                      // A: 128 rows
      gload16(xbf + (size_t)(srcA[p] + tr + koff + ss),
              As + (64 * p + 8 * w) * BK);
    #pragma unroll
    for (int p = 0; p < 4; ++p)                      // B: 256 rows
      gload16(Bsrc + (size_t)(rbase + 64 * p) * 2048 + kq + ss,
              Bs + (64 * p + 8 * w) * BK);
    __syncthreads();
    mma128(As, Bs, lane, wr, wc, acc);
    __syncthreads();
  }
  int m = lane & 15, quad = lane >> 4;
  int bb = (mat < 3 ? (mat * CH + ch) : 0) * 512;
  int cg = b * CH + ch;
  #pragma unroll
  for (int i = 0; i < 4; ++i)
    #pragma unroll
    for (int j = 0; j < 4; ++j)
      #pragma unroll
      for (int e = 0; e < 4; ++e) {
        int row = wr * 64 + i * 16 + quad * 4 + e;
        int pb = mt * 128 + row;
        if (pb >= Pp) continue;
        int tok = pb + 1;
        int n = nbase + wc * 64 + j * 16 + m;        // 0..511
        float bv = (mat < 3) ? beff[bb + n] : 0.f;
        float val = acc[i][j][e] + bv;
        if (mat == 0)      PQ[((size_t)cg * LP + tok) * 512 + n] = f2bs(val);
        else if (mat == 1) PKf[((size_t)cg * LP + tok) * 512 + n] =
                               f2bs(val * QK_SCALE + embz[(size_t)tok * 512 + n]);
        else if (mat == 2) PVt[((size_t)cg * 512 + n) * LP + tok] = f2bs(val);
        else               PX[((size_t)b * LP + tok) * 512 + n] = f2bs(val);
      }
}

// cls row (token 0): one wave per output dot product. grid(128, 3, 2CH)
__global__ void cls_fast(const short* __restrict__ xbf,
                         const float* __restrict__ Wq, const float* __restrict__ bq,
                         const float* __restrict__ Wk, const float* __restrict__ bk,
                         const float* __restrict__ Wv, const float* __restrict__ bv,
                         int h0, int CH,
                         short* __restrict__ PQ, short* __restrict__ PKf,
                         short* __restrict__ PVt) {
  int cg = blockIdx.z, mat = blockIdx.y;
  int wv = threadIdx.x >> 6, lane = threadIdx.x & 63;
  int n = blockIdx.x * 4 + wv;
  int b = cg / CH, h = h0 + cg % CH;
  const float* W = mat == 0 ? Wq : (mat == 1 ? Wk : Wv);
  const float* bias = mat == 0 ? bq : (mat == 1 ? bk : bv);
  const short* xr = xbf + (size_t)b * Ll * 512;
  const float* wr = W + ((size_t)(h * 512 + n)) * 512;
  float s = 0.f;
  #pragma unroll
  for (int j = 0; j < 8; ++j) {
    int k = lane * 8 + j;
    s += bs2f(xr[k]) * wr[k];
  }
  #pragma unroll
  for (int off = 32; off; off >>= 1) s += __shfl_down(s, off, 64);
  if (lane == 0) {
    s += bias[h * 512 + n];
    if (mat == 0)      PQ[((size_t)cg * LP) * 512 + n] = f2bs(s);
    else if (mat == 1) PKf[((size_t)cg * LP) * 512 + n] = f2bs(s * QK_SCALE);
    else               PVt[((size_t)cg * 512 + n) * LP] = f2bs(s);
  }
}

// PX cls row
__global__ void pxcls_kernel(const float* __restrict__ x, short* __restrict__ PX) {
  int b = blockIdx.x, n = threadIdx.x;
  PX[(size_t)b * LP * 512 + n] = f2bs(x[(size_t)b * Ll * 512 + n]);
}

// cfx[cg][kt] = dot(PQ[cg,0,:], embz[kt,:])
__global__ void cfix_kernel(const short* __restrict__ PQ, const float* __restrict__ embz,
                            int a0, float* __restrict__ cfx) {
  int cg = a0 + blockIdx.y;
  int wv = threadIdx.x >> 6, lane = threadIdx.x & 63;
  int kt = blockIdx.x * 4 + wv;
  if (kt >= LP) return;
  int ktc = kt < LL2 ? kt : (LL2 - 1);
  const short* q0 = PQ + (size_t)cg * LP * 512;
  const float* e = embz + (size_t)ktc * 512;
  float s = 0.f;
  #pragma unroll
  for (int j = 0; j < 8; ++j) {
    int d = lane * 8 + j;
    s += bs2f(q0[d]) * e[d];
  }
  #pragma unroll
  for (int off = 32; off; off >>= 1) s += __shfl_down(s, off, 64);
  if (lane == 0) cfx[(size_t)cg * LP + kt] = s;
}

// ===========================================================================
// logits128: Lg[z][q][kt] (bf16) = PQ[cg] . PKf[cg]; row0 -= cfx. grid (13,13,na)
// ===========================================================================
__global__ void logits128(const short* __restrict__ PQ, const short* __restrict__ PKf,
                          const float* __restrict__ cfx, int a0, short* __restrict__ Lg) {
  __shared__ __align__(16) short As[128 * BK];
  __shared__ __align__(16) short Bs[128 * BK];
  int q0 = blockIdx.x * 128, k0 = blockIdx.y * 128, z = blockIdx.z;
  int cg = a0 + z;
  int tid = threadIdx.x, lane = tid & 63, w = tid >> 6, wr = w >> 1, wc = w & 1;
  int rbase = tid >> 3;
  int ss = ((tid & 7) ^ (rbase & 7)) << 3;
  const short* Aq = PQ + (size_t)cg * LP * 512;
  const short* Bk = PKf + (size_t)cg * LP * 512;
  f32x4 acc[4][4] = {};
  for (int kq = 0; kq < 512; kq += BK) {
    #pragma unroll
    for (int p = 0; p < 4; ++p) {
      int row = rbase + 32 * p;
      int ar = q0 + row; if (ar > LL2 - 1) ar = LL2 - 1;
      int br = k0 + row; if (br > LL2 - 1) br = LL2 - 1;
      gload16(Aq + (size_t)ar * 512 + kq + ss, As + (32 * p + 8 * w) * BK);
      gload16(Bk + (size_t)br * 512 + kq + ss, Bs + (32 * p + 8 * w) * BK);
    }
    __syncthreads();
    mma128(As, Bs, lane, wr, wc, acc);
    __syncthreads();
  }
  int m = lane & 15, quad = lane >> 4;
  short* lg = Lg + (size_t)z * LP * LP;
  const float* cf = cfx + (size_t)cg * LP;
  #pragma unroll
  for (int i = 0; i < 4; ++i)
    #pragma unroll
    for (int j = 0; j < 4; ++j)
      #pragma unroll
      for (int e = 0; e < 4; ++e) {
        int q = q0 + wr * 64 + i * 16 + quad * 4 + e;
        int kt = k0 + wc * 64 + j * 16 + m;
        if (q >= LP || kt >= LP) continue;
        float val = acc[i][j][e];
        if (q == 0) val -= cf[kt];
        lg[(size_t)q * LP + kt] = f2bs(val);
      }
}

// softmax: wave-per-row single-pass over bf16 logits (R12). grid (ceil(LL2/4), na).
__global__ void softmax_kernel(short* __restrict__ Lg) {
  int z = blockIdx.y;
  int wv = threadIdx.x >> 6, lane = threadIdx.x & 63;
  int q = blockIdx.x * 4 + wv;
  if (q >= LL2) return;
  short* p = Lg + ((size_t)z * LP + q) * LP;
  float vbuf[32];
  float mx = -1e30f;
  #pragma unroll
  for (int it = 0; it < 4; ++it) {
    int j = it * 512 + lane * 8;
    short8 v = {0, 0, 0, 0, 0, 0, 0, 0};
    if (j < LP) v = *(const short8*)(p + j);
    #pragma unroll
    for (int e = 0; e < 8; ++e) {
      float f = bs2f(v[e]);
      float masked = (j < LP && (j + e) < LL2) ? f : -1e30f;
      vbuf[it * 8 + e] = masked;
      mx = fmaxf(mx, masked);
    }
  }
  #pragma unroll
  for (int off = 32; off; off >>= 1) mx = fmaxf(mx, __shfl_xor(mx, off, 64));
  float sum = 0.f;
  #pragma unroll
  for (int it = 0; it < 4; ++it)
    #pragma unroll
    for (int e = 0; e < 8; ++e) {
      float ev = __expf(vbuf[it * 8 + e] - mx);   // masked -> exp(-huge) = 0
      vbuf[it * 8 + e] = ev;
      sum += ev;
    }
  #pragma unroll
  for (int off = 32; off; off >>= 1) sum += __shfl_xor(sum, off, 64);
  float inv = 1.f / sum;
  #pragma unroll
  for (int it = 0; it < 4; ++it) {
    int j = it * 512 + lane * 8;
    if (j < LP) {
      short8 ov;
      #pragma unroll
      for (int e = 0; e < 8; ++e) ov[e] = f2bs(vbuf[it * 8 + e] * inv);
      *(short8*)(p + j) = ov;
    }
  }
}

// ===========================================================================
// av128: Outb[gg][q][n] = attn @ PVt + (q==0?1:2)*PQ. grid (13,4,na)
// ===========================================================================
__global__ void av128(const short* __restrict__ Lg, const short* __restrict__ PVt,
                      const short* __restrict__ PQ, short* __restrict__ Outb,
                      int h0, int CH, int a0) {
  __shared__ __align__(16) short As[128 * BK];
  __shared__ __align__(16) short Bs[128 * BK];
  int q0 = blockIdx.x * 128, n0 = blockIdx.y * 128, z = blockIdx.z;
  int cg = a0 + z;
  int b = cg / CH, gg = b * 8 + h0 + cg % CH;
  int tid = threadIdx.x, lane = tid & 63, w = tid >> 6, wr = w >> 1, wc = w & 1;
  int rbase = tid >> 3;
  int ss = ((tid & 7) ^ (rbase & 7)) << 3;
  const short* Aat = Lg + (size_t)z * LP * LP;   // bf16 rows, stride LP
  const short* Bv = PVt + (size_t)cg * 512 * LP;
  f32x4 acc[4][4] = {};
  for (int kq = 0; kq < LP; kq += BK) {
    #pragma unroll
    for (int p = 0; p < 4; ++p) {
      int row = rbase + 32 * p;
      int ar = q0 + row; if (ar > LP - 1) ar = LP - 1;
      gload16(Aat + (size_t)ar * LP + kq + ss, As + (32 * p + 8 * w) * BK);
      gload16(Bv + (size_t)(n0 + row) * LP + kq + ss, Bs + (32 * p + 8 * w) * BK);
    }
    __syncthreads();
    mma128(As, Bs, lane, wr, wc, acc);
    __syncthreads();
  }
  int m = lane & 15, quad = lane >> 4;
  #pragma unroll
  for (int i = 0; i < 4; ++i)
    #pragma unroll
    for (int j = 0; j < 4; ++j)
      #pragma unroll
      for (int e = 0; e < 4; ++e) {
        int q = q0 + wr * 64 + i * 16 + quad * 4 + e;
        if (q >= LL2) continue;
        int n = n0 + wc * 64 + j * 16 + m;
        float res = bs2f(PQ[((size_t)cg * LP + q) * 512 + n]);
        float val = acc[i][j][e] + (q == 0 ? 1.f : 2.f) * res;
        Outb[((size_t)gg * LP + q) * 512 + n] = f2bs(val);
      }
}

// ===========================================================================
// final128: Y = stacked @ Wd^T + bd + PX. grid (25, 4). M=3138 flat (b,q).
// ===========================================================================
__global__ void final128(const short* __restrict__ Outb, const short* __restrict__ WdB,
                         const float* __restrict__ bd, const short* __restrict__ PX,
                         float* __restrict__ Y) {
  __shared__ __align__(16) short As[128 * BK];
  __shared__ __align__(16) short Bs[128 * BK];
  int mf0 = blockIdx.x * 128, n0 = blockIdx.y * 128;
  int tid = threadIdx.x, lane = tid & 63, w = tid >> 6, wr = w >> 1, wc = w & 1;
  int rbase = tid >> 3;
  int ss = ((tid & 7) ^ (rbase & 7)) << 3;
  const int M = Bb * LL2;  // 3138
  int brow[4], qrow[4];
  #pragma unroll
  for (int p = 0; p < 4; ++p) {
    int mf = mf0 + rbase + 32 * p; if (mf > M - 1) mf = M - 1;
    brow[p] = mf / LL2; qrow[p] = mf % LL2;
  }
  f32x4 acc[4][4] = {};
  for (int kq = 0; kq < 4096; kq += BK) {
    int hh = kq >> 9, koff = kq & 511;
    #pragma unroll
    for (int p = 0; p < 4; ++p) {
      int row = rbase + 32 * p;
      gload16(Outb + ((size_t)(brow[p] * 8 + hh) * LP + qrow[p]) * 512 + koff + ss,
              As + (32 * p + 8 * w) * BK);
      gload16(WdB + (size_t)(n0 + row) * 4096 + kq + ss,
              Bs + (32 * p + 8 * w) * BK);
    }
    __syncthreads();
    mma128(As, Bs, lane, wr, wc, acc);
    __syncthreads();
  }
  int m = lane & 15, quad = lane >> 4;
  #pragma unroll
  for (int i = 0; i < 4; ++i)
    #pragma unroll
    for (int j = 0; j < 4; ++j)
      #pragma unroll
      for (int e = 0; e < 4; ++e) {
        int mf = mf0 + wr * 64 + i * 16 + quad * 4 + e;
        if (mf >= M) continue;
        int b2 = mf / LL2, q2 = mf % LL2;
        int dm = n0 + wc * 64 + j * 16 + m;
        float val = acc[i][j][e] + bd[dm] + bs2f(PX[((size_t)b2 * LP + q2) * 512 + dm]);
        Y[(size_t)mf * 512 + dm] = val;
      }
}

// LayerNorm over 512
__global__ void ln_kernel(const float* __restrict__ Y, const float* __restrict__ gamma,
                          const float* __restrict__ beta, float* __restrict__ Outp) {
  int row = blockIdx.x;
  const float* y = Y + (size_t)row * 512;
  __shared__ float red[256];
  int tid = threadIdx.x;
  float v0 = y[tid], v1 = y[tid + 256];
  red[tid] = v0 + v1; __syncthreads();
  for (int s = 128; s; s >>= 1) { if (tid < s) red[tid] += red[tid + s]; __syncthreads(); }
  float mu = red[0] * (1.f / 512.f);
  __syncthreads();
  float d0 = v0 - mu, d1 = v1 - mu;
  red[tid] = d0 * d0 + d1 * d1; __syncthreads();
  for (int s = 128; s; s >>= 1) { if (tid < s) red[tid] += red[tid + s]; __syncthreads(); }
  float rstd = rsqrtf(red[0] * (1.f / 512.f) + 1e-5f);
  float* o = Outp + (size_t)row * 512;
  o[tid]       = d0 * rstd * gamma[tid]       + beta[tid];
  o[tid + 256] = d1 * rstd * gamma[tid + 256] + beta[tid + 256];
}

// ---------------------------------------------------------------------------
extern "C" void kernel_launch(void* const* d_in, const int* in_sizes, int n_in,
                              void* d_out, int out_size, void* d_ws, size_t ws_size,
                              hipStream_t stream) {
  const float* x     = (const float*)d_in[0];
  const float* Wq    = (const float*)d_in[1];
  const float* bq    = (const float*)d_in[2];
  const float* Wk    = (const float*)d_in[3];
  const float* bk    = (const float*)d_in[4];
  const float* Wv    = (const float*)d_in[5];
  const float* bv    = (const float*)d_in[6];
  const float* wpq   = (const float*)d_in[7];
  const float* wpk   = (const float*)d_in[8];
  const float* wpv   = (const float*)d_in[9];
  const float* wpx   = (const float*)d_in[10];
  const float* Wd    = (const float*)d_in[11];
  const float* bd    = (const float*)d_in[12];
  const float* gamma = (const float*)d_in[13];
  const float* beta  = (const float*)d_in[14];
  float* outp = (float*)d_out;

  auto rnd = [](size_t b) { return (b + 255) / 256 * 256; };
  const size_t persist =
      rnd((size_t)LP * 512 * 4) +            // embz
      rnd((size_t)Bb * Ll * 512 * 2) +       // xbf
      4 * rnd((size_t)512 * 2048 * 2) +      // wpxT + wpqT/wpkT/wpvT
      3 * rnd((size_t)8 * 512 * 512 * 2) +   // WqT/WkT/WvT
      rnd((size_t)512 * 4096 * 2) +          // WdB
      rnd((size_t)16 * LP * 512 * 2) +       // Outb
      rnd((size_t)2 * LP * 512 * 2) +        // PX
      rnd((size_t)2 * LL2 * 512 * 4) +       // Y
      rnd((size_t)16 * LP * 4);              // cfx
  auto chpart = [&](int CH) {
    return rnd((size_t)3 * CH * 512 * 2048 * 2) + rnd((size_t)3 * CH * 512 * 4) +
           3 * rnd((size_t)2 * CH * LP * 512 * 2);
  };
  const size_t lgbytes = rnd((size_t)LP * LP * 2);   // bf16 Lg (R12)
  int CH = 8;
  while (CH > 1 && persist + chpart(CH) + lgbytes > ws_size) CH >>= 1;
  if (persist + chpart(CH) + lgbytes > ws_size) return;
  int NA = (int)((ws_size - persist - chpart(CH)) / lgbytes);
  if (NA > 2 * CH) NA = 2 * CH;
  int nc = 8 / CH;

  char* w = (char*)d_ws;
  auto alloc = [&](size_t bytes) { char* p = w; w += (bytes + 255) / 256 * 256; return p; };
  float* embz = (float*)alloc((size_t)LP * 512 * 4);
  short* xbf  = (short*)alloc((size_t)Bb * Ll * 512 * 2);
  short* wpxT = (short*)alloc((size_t)512 * 2048 * 2);
  short* wpqT = (short*)alloc((size_t)512 * 2048 * 2);
  short* wpkT = (short*)alloc((size_t)512 * 2048 * 2);
  short* wpvT = (short*)alloc((size_t)512 * 2048 * 2);
  short* WqT  = (short*)alloc((size_t)8 * 512 * 512 * 2);
  short* WkT  = (short*)alloc((size_t)8 * 512 * 512 * 2);
  short* WvT  = (short*)alloc((size_t)8 * 512 * 512 * 2);
  short* WdB  = (short*)alloc((size_t)512 * 4096 * 2);
  short* Outb = (short*)alloc((size_t)16 * LP * 512 * 2);
  short* PX   = (short*)alloc((size_t)2 * LP * 512 * 2);
  float* Y    = (float*)alloc((size_t)2 * LL2 * 512 * 4);
  float* cfx  = (float*)alloc((size_t)16 * LP * 4);
  short* Weff = (short*)alloc((size_t)3 * CH * 512 * 2048 * 2);
  float* beff = (float*)alloc((size_t)3 * CH * 512 * 4);
  short* PQ   = (short*)alloc((size_t)2 * CH * LP * 512 * 2);
  short* PKf  = (short*)alloc((size_t)2 * CH * LP * 512 * 2);
  short* PVt  = (short*)alloc((size_t)2 * CH * LP * 512 * 2);
  short* Lg   = (short*)alloc((size_t)NA * LP * LP * 2);

  dim3 blk(256);
  emb_kernel<<<dim3((LP * 512 + 255) / 256), blk, 0, stream>>>(embz);
  cvt_kernel<<<dim3((Bb * Ll * 512 / 4 + 255) / 256), blk, 0, stream>>>(x, xbf, Bb * Ll * 512 / 4);
  wpxt_kernel<<<dim3(4096), blk, 0, stream>>>(wpx, wpxT);
  wpxt_kernel<<<dim3(4096), blk, 0, stream>>>(wpq, wpqT);
  wpxt_kernel<<<dim3(4096), blk, 0, stream>>>(wpk, wpkT);
  wpxt_kernel<<<dim3(4096), blk, 0, stream>>>(wpv, wpvT);
  tr_w_kernel<<<dim3(8, 8, 8), blk, 0, stream>>>(Wq, WqT);
  tr_w_kernel<<<dim3(8, 8, 8), blk, 0, stream>>>(Wk, WkT);
  tr_w_kernel<<<dim3(8, 8, 8), blk, 0, stream>>>(Wv, WvT);
  cvt_kernel<<<dim3((512 * 4096 / 4 + 255) / 256), blk, 0, stream>>>(Wd, WdB, 512 * 4096 / 4);
  pxcls_kernel<<<dim3(2), dim3(512), 0, stream>>>(x, PX);

  for (int c = 0; c < nc; ++c) {
    int h0 = c * CH;
    weff128<<<dim3(4, 4, 12 * CH), blk, 0, stream>>>(wpqT, wpkT, wpvT, WqT, WkT, WvT,
                                                     h0, CH, Weff);
    beff_fused<<<dim3(3, CH, 4), blk, 0, stream>>>(bq, bk, bv, wpq, wpk, wpv, h0, CH, beff);
    pool512<<<dim3(26 * (6 * CH + 2)), dim3(512), 0, stream>>>(xbf, Weff, wpxT, beff, embz,
                                                               PQ, PKf, PVt, PX, CH);
    cls_fast<<<dim3(128, 3, 2 * CH), blk, 0, stream>>>(xbf, Wq, bq, Wk, bk, Wv, bv,
                                                       h0, CH, PQ, PKf, PVt);
    for (int a0 = 0; a0 < 2 * CH; a0 += NA) {
      int na = (2 * CH - a0) < NA ? (2 * CH - a0) : NA;
      cfix_kernel<<<dim3(400, na), blk, 0, stream>>>(PQ, embz, a0, cfx);
      logits128<<<dim3(13, 13, na), blk, 0, stream>>>(PQ, PKf, cfx, a0, Lg);
      softmax_kernel<<<dim3((LL2 + 3) / 4, na), blk, 0, stream>>>(Lg);
      av128<<<dim3(13, 4, na), blk, 0, stream>>>(Lg, PVt, PQ, Outb, h0, CH, a0);
    }
  }

  final128<<<dim3(25, 4), blk, 0, stream>>>(Outb, WdB, bd, PX, Y);
  ln_kernel<<<dim3(Bb * LL2), blk, 0, stream>>>(Y, gamma, beta, outp);
}